// Round 1
// baseline (1493.443 us; speedup 1.0000x reference)
//
#include <hip/hip_runtime.h>
#include <hip/hip_bf16.h>

// Sizes (fixed by the problem)
#define BATCH 16384
#define IN_F  256
#define H_F   512
#define H2_F  1024
#define MID_F 64
#define NB_F  8

__device__ __forceinline__ float sigmoidf_(float x) { return 1.0f / (1.0f + expf(-x)); }
__device__ __forceinline__ float siluf_(float x)    { return x / (1.0f + expf(-x)); }

// Cox-de Boor recursion, degree 3, 12 knots -> 8 bases. Matches reference exactly
// (>=, < on degree-0; left/right ratios on k=1..3). Knots passed from grid row 0.
__device__ __forceinline__ void bspline8(float x, const float* __restrict__ g, float* __restrict__ out) {
    float b[11];
#pragma unroll
    for (int t = 0; t < 11; ++t)
        b[t] = (x >= g[t] && x < g[t + 1]) ? 1.0f : 0.0f;
#pragma unroll
    for (int k = 1; k <= 3; ++k) {
#pragma unroll
        for (int t = 0; t + k < 11; ++t) {
            float left  = (x - g[t]) / (g[t + k] - g[t]);
            float right = (g[t + k + 1] - x) / (g[t + k + 1] - g[t + 1]);
            b[t] = left * b[t] + right * b[t + 1];
        }
    }
#pragma unroll
    for (int t = 0; t < 8; ++t) out[t] = b[t];
}

// ---------------- prep kernels (tiny, once per call) ----------------

// w1t[(i*8+k)*64+o] = k1_spline[o,i,k] * k1_scaler[o,i]   (layout [i][k][o])
__global__ __launch_bounds__(256) void prep_w1t(const float* __restrict__ k1s,
                                                const float* __restrict__ k1sc,
                                                float* __restrict__ w1t) {
    int t = blockIdx.x * 256 + threadIdx.x;
    if (t >= MID_F * H2_F * NB_F) return;
    int o = t & 63, k = (t >> 6) & 7, i = t >> 9;
    w1t[t] = k1s[(o * H2_F + i) * NB_F + k] * k1sc[o * H2_F + i];
}

// kbt[i*64+o] = k1_base[o,i]
__global__ __launch_bounds__(256) void prep_kbt(const float* __restrict__ k1b,
                                                float* __restrict__ kbt) {
    int t = blockIdx.x * 256 + threadIdx.x;
    if (t >= H2_F * MID_F) return;
    int o = t & 63, i = t >> 6;
    kbt[t] = k1b[o * H2_F + i];
}

// W2aug[o, 0:64] = k2_base ; W2aug[o, 64+i*8+k] = k2_spline[o,i,k]*k2_scaler[o,i]
__global__ __launch_bounds__(256) void prep_w2(const float* __restrict__ k2b,
                                               const float* __restrict__ k2s,
                                               const float* __restrict__ k2sc,
                                               float* __restrict__ w2) {
    int t = blockIdx.x * 256 + threadIdx.x;
    if (t >= H_F * 576) return;
    int o = t / 576, c = t % 576;
    float v;
    if (c < 64) v = k2b[o * MID_F + c];
    else {
        int i = (c - 64) >> 3, k = (c - 64) & 7;
        v = k2s[(o * MID_F + i) * NB_F + k] * k2sc[o * MID_F + i];
    }
    w2[t] = v;
}

// combined[:, 512:1024] = h_prev
__global__ __launch_bounds__(256) void copy_h(const float* __restrict__ hp,
                                              float* __restrict__ comb) {
    int t = blockIdx.x * 256 + threadIdx.x;   // over BATCH*128 float4s
    int b = t >> 7, j = t & 127;
    ((float4*)comb)[b * 256 + 128 + j] = ((const float4*)hp)[t];
}

// ---------------- generic fp32 GEMM: C[m,n] (+)= A[m,:]·W[n,:] + bias[n] ----------------
// M=16384 (grid.x*64), N (grid.y*64), K multiple of 16. A row-major lda, W row-major K.
template<bool ACCUM, bool HASBIAS>
__global__ __launch_bounds__(256) void gemm_nt(const float* __restrict__ A, int lda,
                                               const float* __restrict__ W,
                                               const float* __restrict__ bias,
                                               float* __restrict__ C, int ldc, int K) {
    __shared__ float As[16][68];
    __shared__ float Ws[16][68];
    const int tid = threadIdx.x;
    const int tx = tid & 15, ty = tid >> 4;
    const int m0 = blockIdx.x * 64, n0 = blockIdx.y * 64;
    const int lm = tid >> 2;            // 0..63
    const int lk = (tid & 3) * 4;       // 0,4,8,12
    const float* Arow = A + (size_t)(m0 + lm) * lda + lk;
    const float* Wrow = W + (size_t)(n0 + lm) * K + lk;
    float acc[4][4] = {};
    for (int k0 = 0; k0 < K; k0 += 16) {
        float4 av = *(const float4*)(Arow + k0);
        float4 wv = *(const float4*)(Wrow + k0);
        As[lk + 0][lm] = av.x; As[lk + 1][lm] = av.y; As[lk + 2][lm] = av.z; As[lk + 3][lm] = av.w;
        Ws[lk + 0][lm] = wv.x; Ws[lk + 1][lm] = wv.y; Ws[lk + 2][lm] = wv.z; Ws[lk + 3][lm] = wv.w;
        __syncthreads();
#pragma unroll
        for (int kk = 0; kk < 16; ++kk) {
            float4 a4 = *(const float4*)&As[kk][ty * 4];
            float4 w4 = *(const float4*)&Ws[kk][tx * 4];
            float ar[4] = {a4.x, a4.y, a4.z, a4.w};
            float wr[4] = {w4.x, w4.y, w4.z, w4.w};
#pragma unroll
            for (int r = 0; r < 4; ++r)
#pragma unroll
                for (int c = 0; c < 4; ++c)
                    acc[r][c] += ar[r] * wr[c];
        }
        __syncthreads();
    }
#pragma unroll
    for (int r = 0; r < 4; ++r) {
        int m = m0 + ty * 4 + r;
#pragma unroll
        for (int c = 0; c < 4; ++c) {
            int n = n0 + tx * 4 + c;
            float v = acc[r][c];
            if (HASBIAS) v += bias[n];
            if (ACCUM) C[(size_t)m * ldc + n] += v;
            else       C[(size_t)m * ldc + n] = v;
        }
    }
}

// ---------------- fused KAN layer 1: mid = silu(comb)@k1_base.T + bs(comb)·w1s ----------------
// block = 32 rows x 64 cols, bases computed on the fly in staging.
__global__ __launch_bounds__(256) void kan1_kernel(const float* __restrict__ comb,
                                                   const float* __restrict__ kbt,   // [1024][64]
                                                   const float* __restrict__ w1t,   // [1024][8][64]
                                                   const float* __restrict__ gridp, // knots (12)
                                                   float* __restrict__ mid) {
    __shared__ float s_s[16][33];
    __shared__ float s_b[16][8][33];
    __shared__ float s_kb[16][64];
    __shared__ float s_w[16][8][64];
    float g[12];
#pragma unroll
    for (int t = 0; t < 12; ++t) g[t] = gridp[t];
    const int tid = threadIdx.x;
    const int tx = tid & 15, ty = tid >> 4;
    const int m0 = blockIdx.x * 32;
    float acc0[4] = {}, acc1[4] = {};
    for (int i0 = 0; i0 < H2_F; i0 += 16) {
        // stage combined tile + compute silu/bases: 32 rows x 16 i
#pragma unroll
        for (int p = tid; p < 512; p += 256) {
            int ii = p & 15, m = p >> 4;
            float xv = comb[(size_t)(m0 + m) * H2_F + i0 + ii];
            s_s[ii][m] = siluf_(xv);
            float bb[8];
            bspline8(xv, g, bb);
#pragma unroll
            for (int k = 0; k < 8; ++k) s_b[ii][k][m] = bb[k];
        }
        {   // kb tile: 1024 floats contiguous
            float4 v = ((const float4*)(kbt + i0 * 64))[tid];
            ((float4*)&s_kb[0][0])[tid] = v;
        }
        {   // w tile: 8192 floats contiguous
            const float4* src = (const float4*)(w1t + (size_t)i0 * 512);
            float4* dst = (float4*)&s_w[0][0][0];
#pragma unroll
            for (int p = tid; p < 2048; p += 256) dst[p] = src[p];
        }
        __syncthreads();
#pragma unroll
        for (int ii = 0; ii < 16; ++ii) {
            float a0 = s_s[ii][ty * 2], a1 = s_s[ii][ty * 2 + 1];
#pragma unroll
            for (int c = 0; c < 4; ++c) {
                float wv = s_kb[ii][tx * 4 + c];
                acc0[c] += a0 * wv; acc1[c] += a1 * wv;
            }
#pragma unroll
            for (int k = 0; k < 8; ++k) {
                float b0 = s_b[ii][k][ty * 2], b1 = s_b[ii][k][ty * 2 + 1];
#pragma unroll
                for (int c = 0; c < 4; ++c) {
                    float wv = s_w[ii][k][tx * 4 + c];
                    acc0[c] += b0 * wv; acc1[c] += b1 * wv;
                }
            }
        }
        __syncthreads();
    }
    int m = m0 + ty * 2;
#pragma unroll
    for (int c = 0; c < 4; ++c) {
        mid[(size_t)m * 64 + tx * 4 + c]       = acc0[c];
        mid[(size_t)(m + 1) * 64 + tx * 4 + c] = acc1[c];
    }
}

// ---------------- A2 = [silu(mid) | bases(mid)]  (B x 576) ----------------
__global__ __launch_bounds__(256) void bs2_kernel(const float* __restrict__ midp,
                                                  const float* __restrict__ gridp,
                                                  float* __restrict__ A2) {
    int t = blockIdx.x * 256 + threadIdx.x;
    if (t >= BATCH * MID_F) return;
    int b = t >> 6, i = t & 63;
    float g[12];
#pragma unroll
    for (int tt = 0; tt < 12; ++tt) g[tt] = gridp[tt];
    float xv = midp[t];
    A2[(size_t)b * 576 + i] = siluf_(xv);
    float bb[8];
    bspline8(xv, g, bb);
#pragma unroll
    for (int k = 0; k < 8; ++k) A2[(size_t)b * 576 + 64 + i * 8 + k] = bb[k];
}

// ---------------- reductions ----------------
__device__ __forceinline__ void block_reduce_2(float& a, float& b, float (*red)[4]) {
#pragma unroll
    for (int off = 32; off; off >>= 1) {
        a += __shfl_xor(a, off, 64);
        b += __shfl_xor(b, off, 64);
    }
    int lane = threadIdx.x & 63, wid = threadIdx.x >> 6;
    if (lane == 0) { red[0][wid] = a; red[1][wid] = b; }
    __syncthreads();
    a = red[0][0] + red[0][1] + red[0][2] + red[0][3];
    b = red[1][0] + red[1][1] + red[1][2] + red[1][3];
}

// update = sigmoid(LN(ug_pre)) -> out (used as scratch for the gate)
__global__ __launch_bounds__(256) void ln_sigmoid_kernel(const float* __restrict__ in,
                                                         const float* __restrict__ gg,
                                                         const float* __restrict__ bb,
                                                         float* __restrict__ out) {
    int row = blockIdx.x, tid = threadIdx.x;
    __shared__ float red[2][4];
    const float* v = in + (size_t)row * 512;
    float x0 = v[tid], x1 = v[tid + 256];
    float s = x0 + x1, ss = x0 * x0 + x1 * x1;
    block_reduce_2(s, ss, red);
    float mu = s * (1.0f / 512.0f);
    float var = ss * (1.0f / 512.0f) - mu * mu;
    float r = rsqrtf(var + 1e-5f);
    float y0 = (x0 - mu) * r * gg[tid] + bb[tid];
    float y1 = (x1 - mu) * r * gg[tid + 256] + bb[tid + 256];
    out[(size_t)row * 512 + tid]       = sigmoidf_(y0);
    out[(size_t)row * 512 + tid + 256] = sigmoidf_(y1);
}

// h_t = (1-u)*h_prev + u*silu(LN(LN(hc)))   (u already in out)
__global__ __launch_bounds__(256) void final_kernel(const float* __restrict__ hc,
                                                    const float* __restrict__ hprev,
                                                    const float* __restrict__ cg,
                                                    const float* __restrict__ cb,
                                                    float* __restrict__ out) {
    int row = blockIdx.x, tid = threadIdx.x;
    __shared__ float redA[2][4];
    __shared__ float redB[2][4];
    const float* v = hc + (size_t)row * 512;
    float x0 = v[tid], x1 = v[tid + 256];
    float g0 = cg[tid], g1 = cg[tid + 256];
    float b0 = cb[tid], b1 = cb[tid + 256];
    float s = x0 + x1, ss = x0 * x0 + x1 * x1;
    block_reduce_2(s, ss, redA);
    float mu = s * (1.0f / 512.0f);
    float var = ss * (1.0f / 512.0f) - mu * mu;
    float r = rsqrtf(var + 1e-5f);
    float w0 = (x0 - mu) * r * g0 + b0;
    float w1 = (x1 - mu) * r * g1 + b1;
    float s2 = w0 + w1, ss2 = w0 * w0 + w1 * w1;
    block_reduce_2(s2, ss2, redB);
    float mu2 = s2 * (1.0f / 512.0f);
    float var2 = ss2 * (1.0f / 512.0f) - mu2 * mu2;
    float r2 = rsqrtf(var2 + 1e-5f);
    float z0 = (w0 - mu2) * r2 * g0 + b0;
    float z1 = (w1 - mu2) * r2 * g1 + b1;
    float c0 = siluf_(z0), c1 = siluf_(z1);
    size_t o0 = (size_t)row * 512 + tid, o1 = o0 + 256;
    float u0 = out[o0], u1 = out[o1];
    float hp0 = hprev[o0], hp1 = hprev[o1];
    out[o0] = (1.0f - u0) * hp0 + u0 * c0;
    out[o1] = (1.0f - u1) * hp1 + u1 * c1;
}

extern "C" void kernel_launch(void* const* d_in, const int* in_sizes, int n_in,
                              void* d_out, int out_size, void* d_ws, size_t ws_size,
                              hipStream_t stream) {
    const float* x        = (const float*)d_in[0];
    const float* h_prev   = (const float*)d_in[1];
    const float* ip_w     = (const float*)d_in[2];
    const float* ip_b     = (const float*)d_in[3];
    // d_in[4..7] = rg_* : dead code (reset gate never used in h_t)
    const float* ug_w     = (const float*)d_in[8];
    const float* ug_b     = (const float*)d_in[9];
    const float* ug_g     = (const float*)d_in[10];
    const float* ug_beta  = (const float*)d_in[11];
    const float* k1_base  = (const float*)d_in[12];
    const float* k1_spline= (const float*)d_in[13];
    const float* k1_scaler= (const float*)d_in[14];
    const float* grid1    = (const float*)d_in[15];
    const float* k2_base  = (const float*)d_in[16];
    const float* k2_spline= (const float*)d_in[17];
    const float* k2_scaler= (const float*)d_in[18];
    const float* grid2    = (const float*)d_in[19];
    const float* cn_g     = (const float*)d_in[20];
    const float* cn_b     = (const float*)d_in[21];
    const float* rp_w     = (const float*)d_in[22];
    const float* rp_b     = (const float*)d_in[23];
    float* out = (float*)d_out;
    float* ws  = (float*)d_ws;

    // workspace layout (floats)
    float* combined = ws;                        // 16384*1024 = 16,777,216
    float* tmp512   = ws + 16777216;             // 16384*512  =  8,388,608
    float* midb     = ws + 25165824;             // 16384*64   =  1,048,576
    float* A2       = ws + 26214400;             // 16384*576  =  9,437,184
    float* w1t      = ws + 35651584;             // 64*1024*8  =    524,288
    float* kbt      = ws + 36175872;             // 1024*64    =     65,536
    float* w2aug    = ws + 36241408;             // 512*576    =    294,912

    // weight prep
    hipLaunchKernelGGL(prep_w1t, dim3(2048), dim3(256), 0, stream, k1_spline, k1_scaler, w1t);
    hipLaunchKernelGGL(prep_kbt, dim3(256), dim3(256), 0, stream, k1_base, kbt);
    hipLaunchKernelGGL(prep_w2, dim3(1152), dim3(256), 0, stream, k2_base, k2_spline, k2_scaler, w2aug);

    // combined = [x@ip_w.T + ip_b , h_prev]
    hipLaunchKernelGGL((gemm_nt<false, true>), dim3(BATCH / 64, H_F / 64), dim3(256), 0, stream,
                       x, IN_F, ip_w, ip_b, combined, H2_F, IN_F);
    hipLaunchKernelGGL(copy_h, dim3(BATCH * 128 / 256), dim3(256), 0, stream, h_prev, combined);

    // update gate: tmp512 = combined@ug_w.T + ug_b ; out = sigmoid(LN(tmp512))
    hipLaunchKernelGGL((gemm_nt<false, true>), dim3(BATCH / 64, H_F / 64), dim3(256), 0, stream,
                       combined, H2_F, ug_w, ug_b, tmp512, H_F, H2_F);
    hipLaunchKernelGGL(ln_sigmoid_kernel, dim3(BATCH), dim3(256), 0, stream, tmp512, ug_g, ug_beta, out);

    // KAN layer 1 -> mid ; then A2 = [silu(mid) | bases(mid)]
    hipLaunchKernelGGL(kan1_kernel, dim3(BATCH / 32), dim3(256), 0, stream, combined, kbt, w1t, grid1, midb);
    hipLaunchKernelGGL(bs2_kernel, dim3(BATCH * 64 / 256), dim3(256), 0, stream, midb, grid2, A2);

    // residual + KAN layer 2 (accumulated)
    hipLaunchKernelGGL((gemm_nt<false, true>), dim3(BATCH / 64, H_F / 64), dim3(256), 0, stream,
                       combined, H2_F, rp_w, rp_b, tmp512, H_F, H2_F);
    hipLaunchKernelGGL((gemm_nt<true, false>), dim3(BATCH / 64, H_F / 64), dim3(256), 0, stream,
                       A2, 576, w2aug, (const float*)nullptr, tmp512, H_F, 576);

    // h_t
    hipLaunchKernelGGL(final_kernel, dim3(BATCH), dim3(256), 0, stream, tmp512, h_prev, cn_g, cn_b, out);
}

// Round 2
// 302.291 us; speedup vs baseline: 4.9404x; 4.9404x over previous
//
#include <hip/hip_runtime.h>
#include <hip/hip_bf16.h>

#define BATCH 16384
#define H_F   512
#define H2_F  1024

typedef __attribute__((ext_vector_type(8))) short short8;
typedef __attribute__((ext_vector_type(4))) float f32x4;

typedef const __attribute__((address_space(1))) uint* gas_t;
typedef __attribute__((address_space(3))) uint* las_t;

__device__ __forceinline__ void gl_lds16(const void* g, void* l) {
    __builtin_amdgcn_global_load_lds((gas_t)g, (las_t)l, 16, 0, 0);
}

__device__ __forceinline__ float bf2f(uint u) { union { uint u; float f; } v; v.u = u << 16; return v.f; }
__device__ __forceinline__ ushort f2bf(float f) {
    union { float f; uint u; } v; v.f = f;
    uint r = v.u + 0x7fffu + ((v.u >> 16) & 1u);
    return (ushort)(r >> 16);
}
__device__ __forceinline__ uint pack2(float a, float b) { return (uint)f2bf(a) | ((uint)f2bf(b) << 16); }
__device__ __forceinline__ float sigmoidf_(float x) { return 1.0f / (1.0f + expf(-x)); }
__device__ __forceinline__ float siluf_(float x)    { return x / (1.0f + expf(-x)); }

// Uniform cubic B-spline, branchless, all 8 bases. u = (x-g0)/h.
// b_t = N(u-t), N supported on [0,4). Matches reference Cox-de Boor exactly
// (continuous; half-open boundaries coincide).
__device__ __forceinline__ void bspline8_all(float u, float bb[8]) {
#pragma unroll
    for (int t = 0; t < 8; ++t) {
        float y = fabsf(u - (float)t - 2.0f);
        float y2 = y * y;
        float p1 = y2 * (0.5f * y - 1.0f) + (2.0f / 3.0f); // (3y^3-6y^2+4)/6
        float q = 2.0f - y;
        float p2 = q * q * q * (1.0f / 6.0f);
        float v = (y < 1.0f) ? p1 : p2;
        bb[t] = (y < 2.0f) ? v : 0.0f;
    }
}

// ---------------- prep kernels ----------------

// fp32 -> bf16, 8 elems/thread
__global__ __launch_bounds__(256) void cvt_bf(const float* __restrict__ src, ushort* __restrict__ dst, int n8) {
    int t = blockIdx.x * 256 + threadIdx.x;
    if (t >= n8) return;
    const float4* s = (const float4*)src;
    float4 a = s[t * 2], b = s[t * 2 + 1];
    uint4 o; o.x = pack2(a.x, a.y); o.y = pack2(a.z, a.w); o.z = pack2(b.x, b.y); o.w = pack2(b.z, b.w);
    ((uint4*)dst)[t] = o;
}

// combined_bf[:, 512:1024] = bf16(h_prev)
__global__ __launch_bounds__(256) void copy_h_bf(const float* __restrict__ hp, ushort* __restrict__ comb) {
    int t = blockIdx.x * 256 + threadIdx.x;          // BATCH*512/8
    int b = t >> 6, j = (t & 63) * 8;
    const float4* s = (const float4*)(hp + (size_t)b * 512 + j);
    float4 a = s[0], c = s[1];
    uint4 o; o.x = pack2(a.x, a.y); o.y = pack2(a.z, a.w); o.z = pack2(c.x, c.y); o.w = pack2(c.z, c.w);
    *(uint4*)(comb + (size_t)b * 1024 + 512 + j) = o;
}

// w1aug[o][c] : c<1024 -> k1_base[o][c] ; else c=1024+i*8+k -> k1_spline[o][i][k]*k1_scaler[o][i]
__global__ __launch_bounds__(256) void prep_w1aug(const float* __restrict__ k1b, const float* __restrict__ k1s,
                                                  const float* __restrict__ k1sc, ushort* __restrict__ w) {
    int t = blockIdx.x * 256 + threadIdx.x;
    if (t >= 64 * 9216) return;
    int o = t / 9216, c = t % 9216;
    float v;
    if (c < 1024) v = k1b[o * 1024 + c];
    else { int i = (c - 1024) >> 3, k = (c - 1024) & 7; v = k1s[(o * 1024 + i) * 8 + k] * k1sc[o * 1024 + i]; }
    w[t] = f2bf(v);
}

// w2aug[o][c] : c<64 -> k2_base ; else spline*scaler
__global__ __launch_bounds__(256) void prep_w2aug(const float* __restrict__ k2b, const float* __restrict__ k2s,
                                                  const float* __restrict__ k2sc, ushort* __restrict__ w) {
    int t = blockIdx.x * 256 + threadIdx.x;
    if (t >= 512 * 576) return;
    int o = t / 576, c = t % 576;
    float v;
    if (c < 64) v = k2b[o * 64 + c];
    else { int i = (c - 64) >> 3, k = (c - 64) & 7; v = k2s[(o * 64 + i) * 8 + k] * k2sc[o * 64 + i]; }
    w[t] = f2bf(v);
}

// ---------------- MFMA GEMM: C[m,n] (+)= A[m,:]·W[n,:]^T + bias[n] ----------------
// A bf16 [M][lda], W bf16 [N][ldw] (ldw=K), C fp32 or bf16. 128x128 tile, BK=32, 4 waves.
template<bool ACCUM, bool BF16OUT, bool HASBIAS>
__global__ __launch_bounds__(256) void gemm_mfma(const ushort* __restrict__ A, int lda,
                                                 const ushort* __restrict__ Wt, int ldw,
                                                 const float* __restrict__ bias,
                                                 void* __restrict__ Cv, int ldc, int K) {
    __shared__ ushort As[128][32];
    __shared__ ushort Bs[128][32];
    const int tid = threadIdx.x;
    const int w = tid >> 6, lane = tid & 63;
    const int fr = lane & 15, fq = lane >> 4;
    const int m0 = blockIdx.x * 128, n0 = blockIdx.y * 128;
    const int wm = w & 1, wn = w >> 1;

    // staging: 8KB per tile = 8 wave-chunks of 1KB; chunk = j*4+w, lane covers 16B
    const int fa0 = (0 * 4 + w) * 512 + lane * 8;
    const int fa1 = (1 * 4 + w) * 512 + lane * 8;
    const ushort* gA0 = A  + (size_t)(m0 + fa0 / 32) * lda + (fa0 % 32);
    const ushort* gA1 = A  + (size_t)(m0 + fa1 / 32) * lda + (fa1 % 32);
    const ushort* gB0 = Wt + (size_t)(n0 + fa0 / 32) * ldw + (fa0 % 32);
    const ushort* gB1 = Wt + (size_t)(n0 + fa1 / 32) * ldw + (fa1 % 32);
    ushort* lA0 = &As[0][0] + (0 * 4 + w) * 512;
    ushort* lA1 = &As[0][0] + (1 * 4 + w) * 512;
    ushort* lB0 = &Bs[0][0] + (0 * 4 + w) * 512;
    ushort* lB1 = &Bs[0][0] + (1 * 4 + w) * 512;

    const ushort* aRd = &As[0][0] + (wm * 64 + fr) * 32 + fq * 8;
    const ushort* bRd = &Bs[0][0] + (wn * 64 + fr) * 32 + fq * 8;

    f32x4 acc[4][4] = {};
    for (int k0 = 0; k0 < K; k0 += 32) {
        gl_lds16(gA0, lA0); gl_lds16(gA1, lA1);
        gl_lds16(gB0, lB0); gl_lds16(gB1, lB1);
        gA0 += 32; gA1 += 32; gB0 += 32; gB1 += 32;
        __syncthreads();
        short8 af[4], bf[4];
#pragma unroll
        for (int mi = 0; mi < 4; ++mi) af[mi] = *(const short8*)(aRd + mi * 512);
#pragma unroll
        for (int ni = 0; ni < 4; ++ni) bf[ni] = *(const short8*)(bRd + ni * 512);
#pragma unroll
        for (int mi = 0; mi < 4; ++mi)
#pragma unroll
            for (int ni = 0; ni < 4; ++ni)
                acc[mi][ni] = __builtin_amdgcn_mfma_f32_16x16x32_bf16(af[mi], bf[ni], acc[mi][ni], 0, 0, 0);
        __syncthreads();
    }
#pragma unroll
    for (int mi = 0; mi < 4; ++mi) {
#pragma unroll
        for (int ni = 0; ni < 4; ++ni) {
            int n = n0 + wn * 64 + ni * 16 + fr;
            float bv = HASBIAS ? bias[n] : 0.0f;
#pragma unroll
            for (int r = 0; r < 4; ++r) {
                int m = m0 + wm * 64 + mi * 16 + fq * 4 + r;
                float val = acc[mi][ni][r] + bv;
                if (BF16OUT)      ((ushort*)Cv)[(size_t)m * ldc + n] = f2bf(val);
                else if (ACCUM)   ((float*)Cv)[(size_t)m * ldc + n] += val;
                else              ((float*)Cv)[(size_t)m * ldc + n] = val;
            }
        }
    }
}

// ---------------- KAN layer 1 via MFMA, bases computed in staging ----------------
// A_aug cols: [0,1024) = silu(comb), [1024,9216) = 1024+i*8+k -> basis k of comb[:,i]
// grid.x = M/64, grid.y = 2 (K halves). Output mid[kb][B][64] partials (f32).
__global__ __launch_bounds__(256) void kan1_mfma(const ushort* __restrict__ comb,   // [B][1024] bf16
                                                 const ushort* __restrict__ w1aug,  // [64][9216] bf16
                                                 const float* __restrict__ grid1,
                                                 float* __restrict__ midp) {
    __shared__ ushort As[64][32];
    __shared__ ushort Bs[64][32];
    const int tid = threadIdx.x;
    const int w = tid >> 6, lane = tid & 63;
    const int fr = lane & 15, fq = lane >> 4;
    const int m0 = blockIdx.x * 64;
    const int kb = blockIdx.y;
    const int kstart = kb * 4608, kend = kstart + 4608;
    const float g0 = grid1[0];
    const float inv_h = 1.0f / (grid1[1] - g0);

    // B staging: 64x32 = 4KB: chunk = w, lane 16B
    const int fb = w * 512 + lane * 8;
    const ushort* gB = w1aug + (size_t)(fb / 32) * 9216 + kstart + (fb % 32);
    ushort* lB = &Bs[0][0] + w * 512;

    // A staging roles: thread -> (row = tid/4, quarter = tid&3)
    const int srow = tid >> 2, sq = tid & 3;

    const ushort* aRd = &As[0][0] + (w * 16 + fr) * 32 + fq * 8;
    const ushort* bRd = &Bs[0][0] + fr * 32 + fq * 8;

    f32x4 acc[4] = {};
    for (int k0 = kstart; k0 < kend; k0 += 32) {
        gl_lds16(gB, lB); gB += 32;
        uint4 o;
        if (k0 + 32 <= 1024) {
            // silu region: 8 contiguous comb elems
            const ushort* src = comb + (size_t)(m0 + srow) * 1024 + k0 + sq * 8;
            uint4 raw = *(const uint4*)src;
            uint rr[4] = {raw.x, raw.y, raw.z, raw.w};
            uint oo[4];
#pragma unroll
            for (int p = 0; p < 4; ++p) {
                float lo = siluf_(bf2f(rr[p] & 0xffffu));
                float hi = siluf_(bf2f(rr[p] >> 16));
                oo[p] = pack2(lo, hi);
            }
            o.x = oo[0]; o.y = oo[1]; o.z = oo[2]; o.w = oo[3];
        } else {
            // basis region: this thread owns input feature i, all 8 bases
            int i = ((k0 - 1024) >> 3) + sq;
            float x = bf2f((uint)comb[(size_t)(m0 + srow) * 1024 + i]);
            float bb[8];
            bspline8_all((x - g0) * inv_h, bb);
            o.x = pack2(bb[0], bb[1]); o.y = pack2(bb[2], bb[3]);
            o.z = pack2(bb[4], bb[5]); o.w = pack2(bb[6], bb[7]);
        }
        *(uint4*)&As[srow][sq * 8] = o;
        __syncthreads();
        short8 af = *(const short8*)aRd;
#pragma unroll
        for (int ni = 0; ni < 4; ++ni) {
            short8 bfv = *(const short8*)(bRd + ni * 512);
            acc[ni] = __builtin_amdgcn_mfma_f32_16x16x32_bf16(af, bfv, acc[ni], 0, 0, 0);
        }
        __syncthreads();
    }
    float* outp = midp + (size_t)kb * (BATCH * 64);
#pragma unroll
    for (int ni = 0; ni < 4; ++ni)
#pragma unroll
        for (int r = 0; r < 4; ++r)
            outp[(size_t)(m0 + w * 16 + fq * 4 + r) * 64 + ni * 16 + fr] = acc[ni][r];
}

// ---------------- A2 = [silu(mid) | bases(mid)] bf16, summing split-K partials ----------------
__global__ __launch_bounds__(256) void bs2_kernel(const float* __restrict__ midp,
                                                  const float* __restrict__ grid2,
                                                  ushort* __restrict__ A2) {
    int t = blockIdx.x * 256 + threadIdx.x;     // B*64
    if (t >= BATCH * 64) return;
    int b = t >> 6, i = t & 63;
    float x = midp[t] + midp[BATCH * 64 + t];
    float g0 = grid2[0];
    float inv_h = 1.0f / (grid2[1] - g0);
    A2[(size_t)b * 576 + i] = f2bf(siluf_(x));
    float bb[8];
    bspline8_all((x - g0) * inv_h, bb);
    uint4 o;
    o.x = pack2(bb[0], bb[1]); o.y = pack2(bb[2], bb[3]);
    o.z = pack2(bb[4], bb[5]); o.w = pack2(bb[6], bb[7]);
    *(uint4*)&A2[(size_t)b * 576 + 64 + i * 8] = o;
}

// ---------------- LayerNorm kernels ----------------
__device__ __forceinline__ void block_reduce_2(float& a, float& b, float (*red)[4]) {
#pragma unroll
    for (int off = 32; off; off >>= 1) {
        a += __shfl_xor(a, off, 64);
        b += __shfl_xor(b, off, 64);
    }
    int lane = threadIdx.x & 63, wid = threadIdx.x >> 6;
    if (lane == 0) { red[0][wid] = a; red[1][wid] = b; }
    __syncthreads();
    a = red[0][0] + red[0][1] + red[0][2] + red[0][3];
    b = red[1][0] + red[1][1] + red[1][2] + red[1][3];
}

__global__ __launch_bounds__(256) void ln_sigmoid_kernel(const float* __restrict__ in,
                                                         const float* __restrict__ gg,
                                                         const float* __restrict__ bb,
                                                         float* __restrict__ out) {
    int row = blockIdx.x, tid = threadIdx.x;
    __shared__ float red[2][4];
    const float* v = in + (size_t)row * 512;
    float x0 = v[tid], x1 = v[tid + 256];
    float s = x0 + x1, ss = x0 * x0 + x1 * x1;
    block_reduce_2(s, ss, red);
    float mu = s * (1.0f / 512.0f);
    float var = ss * (1.0f / 512.0f) - mu * mu;
    float r = rsqrtf(var + 1e-5f);
    float y0 = (x0 - mu) * r * gg[tid] + bb[tid];
    float y1 = (x1 - mu) * r * gg[tid + 256] + bb[tid + 256];
    out[(size_t)row * 512 + tid]       = sigmoidf_(y0);
    out[(size_t)row * 512 + tid + 256] = sigmoidf_(y1);
}

__global__ __launch_bounds__(256) void final_kernel(const float* __restrict__ hc,
                                                    const float* __restrict__ hprev,
                                                    const float* __restrict__ cg,
                                                    const float* __restrict__ cb,
                                                    float* __restrict__ out) {
    int row = blockIdx.x, tid = threadIdx.x;
    __shared__ float redA[2][4];
    __shared__ float redB[2][4];
    const float* v = hc + (size_t)row * 512;
    float x0 = v[tid], x1 = v[tid + 256];
    float g0 = cg[tid], g1 = cg[tid + 256];
    float b0 = cb[tid], b1 = cb[tid + 256];
    float s = x0 + x1, ss = x0 * x0 + x1 * x1;
    block_reduce_2(s, ss, redA);
    float mu = s * (1.0f / 512.0f);
    float var = ss * (1.0f / 512.0f) - mu * mu;
    float r = rsqrtf(var + 1e-5f);
    float w0 = (x0 - mu) * r * g0 + b0;
    float w1 = (x1 - mu) * r * g1 + b1;
    float s2 = w0 + w1, ss2 = w0 * w0 + w1 * w1;
    block_reduce_2(s2, ss2, redB);
    float mu2 = s2 * (1.0f / 512.0f);
    float var2 = ss2 * (1.0f / 512.0f) - mu2 * mu2;
    float r2 = rsqrtf(var2 + 1e-5f);
    float z0 = (w0 - mu2) * r2 * g0 + b0;
    float z1 = (w1 - mu2) * r2 * g1 + b1;
    float c0 = siluf_(z0), c1 = siluf_(z1);
    size_t o0 = (size_t)row * 512 + tid, o1 = o0 + 256;
    float u0 = out[o0], u1 = out[o1];
    float hp0 = hprev[o0], hp1 = hprev[o1];
    out[o0] = (1.0f - u0) * hp0 + u0 * c0;
    out[o1] = (1.0f - u1) * hp1 + u1 * c1;
}

extern "C" void kernel_launch(void* const* d_in, const int* in_sizes, int n_in,
                              void* d_out, int out_size, void* d_ws, size_t ws_size,
                              hipStream_t stream) {
    const float* x        = (const float*)d_in[0];
    const float* h_prev   = (const float*)d_in[1];
    const float* ip_w     = (const float*)d_in[2];
    const float* ip_b     = (const float*)d_in[3];
    // d_in[4..7] rg_* : dead (reset gate unused in h_t)
    const float* ug_w     = (const float*)d_in[8];
    const float* ug_b     = (const float*)d_in[9];
    const float* ug_g     = (const float*)d_in[10];
    const float* ug_beta  = (const float*)d_in[11];
    const float* k1_base  = (const float*)d_in[12];
    const float* k1_spline= (const float*)d_in[13];
    const float* k1_scaler= (const float*)d_in[14];
    const float* grid1    = (const float*)d_in[15];
    const float* k2_base  = (const float*)d_in[16];
    const float* k2_spline= (const float*)d_in[17];
    const float* k2_scaler= (const float*)d_in[18];
    const float* grid2    = (const float*)d_in[19];
    const float* cn_g     = (const float*)d_in[20];
    const float* cn_b     = (const float*)d_in[21];
    const float* rp_w     = (const float*)d_in[22];
    const float* rp_b     = (const float*)d_in[23];
    float* out = (float*)d_out;
    char* W = (char*)d_ws;

    ushort* x_bf    = (ushort*)(W);                   //  8,388,608 B
    ushort* comb_bf = (ushort*)(W + 8388608);         // 33,554,432 B
    float*  ug_pre  = (float*) (W + 41943040);        // 33,554,432 B
    float*  hc      = (float*) (W + 75497472);        // 33,554,432 B
    float*  midp    = (float*) (W + 109051904);       //  8,388,608 B (2 halves)
    ushort* A2_bf   = (ushort*)(W + 117440512);       // 18,874,368 B
    ushort* ipw_bf  = (ushort*)(W + 136314880);       //    262,144 B
    ushort* ugw_bf  = (ushort*)(W + 136577024);       //  1,048,576 B
    ushort* rpw_bf  = (ushort*)(W + 137625600);       //  1,048,576 B
    ushort* w1aug   = (ushort*)(W + 138674176);       //  1,179,648 B
    ushort* w2aug   = (ushort*)(W + 139853824);       //    589,824 B

    // --- prep (bf16 conversions / weight flattening) ---
    hipLaunchKernelGGL(cvt_bf, dim3(2048), dim3(256), 0, stream, x, x_bf, BATCH * 256 / 8);
    hipLaunchKernelGGL(cvt_bf, dim3(64),   dim3(256), 0, stream, ip_w, ipw_bf, 512 * 256 / 8);
    hipLaunchKernelGGL(cvt_bf, dim3(256),  dim3(256), 0, stream, ug_w, ugw_bf, 512 * 1024 / 8);
    hipLaunchKernelGGL(cvt_bf, dim3(256),  dim3(256), 0, stream, rp_w, rpw_bf, 512 * 1024 / 8);
    hipLaunchKernelGGL(prep_w1aug, dim3((64 * 9216 + 255) / 256), dim3(256), 0, stream, k1_base, k1_spline, k1_scaler, w1aug);
    hipLaunchKernelGGL(prep_w2aug, dim3((512 * 576 + 255) / 256), dim3(256), 0, stream, k2_base, k2_spline, k2_scaler, w2aug);
    hipLaunchKernelGGL(copy_h_bf, dim3(BATCH * 512 / 8 / 256), dim3(256), 0, stream, h_prev, comb_bf);

    // --- combined[:, :512] = bf16(x @ ip_w.T + ip_b) ---
    hipLaunchKernelGGL((gemm_mfma<false, true, true>), dim3(BATCH / 128, 4), dim3(256), 0, stream,
                       x_bf, 256, ipw_bf, 256, ip_b, comb_bf, 1024, 256);

    // --- update gate ---
    hipLaunchKernelGGL((gemm_mfma<false, false, true>), dim3(BATCH / 128, 4), dim3(256), 0, stream,
                       comb_bf, 1024, ugw_bf, 1024, ug_b, ug_pre, 512, 1024);
    hipLaunchKernelGGL(ln_sigmoid_kernel, dim3(BATCH), dim3(256), 0, stream, ug_pre, ug_g, ug_beta, out);

    // --- KAN1 (split-K=2) -> mid partials -> A2 ---
    hipLaunchKernelGGL(kan1_mfma, dim3(BATCH / 64, 2), dim3(256), 0, stream, comb_bf, w1aug, grid1, midp);
    hipLaunchKernelGGL(bs2_kernel, dim3(BATCH * 64 / 256), dim3(256), 0, stream, midp, grid2, A2_bf);

    // --- residual + KAN2 ---
    hipLaunchKernelGGL((gemm_mfma<false, false, true>), dim3(BATCH / 128, 4), dim3(256), 0, stream,
                       comb_bf, 1024, rpw_bf, 1024, rp_b, hc, 512, 1024);
    hipLaunchKernelGGL((gemm_mfma<true, false, false>), dim3(BATCH / 128, 4), dim3(256), 0, stream,
                       A2_bf, 576, w2aug, 576, (const float*)nullptr, hc, 512, 576);

    // --- h_t ---
    hipLaunchKernelGGL(final_kernel, dim3(BATCH), dim3(256), 0, stream, hc, h_prev, cn_g, cn_b, out);
}

// Round 3
// 239.078 us; speedup vs baseline: 6.2467x; 1.2644x over previous
//
#include <hip/hip_runtime.h>
#include <hip/hip_bf16.h>

#define BATCH 16384

typedef __attribute__((ext_vector_type(8))) short short8;
typedef __attribute__((ext_vector_type(4))) float f32x4;

typedef const __attribute__((address_space(1))) uint* gas_t;
typedef __attribute__((address_space(3))) uint* las_t;

__device__ __forceinline__ void gl_lds16(const void* g, void* l) {
    __builtin_amdgcn_global_load_lds((gas_t)g, (las_t)l, 16, 0, 0);
}

__device__ __forceinline__ float bf2f(uint u) { union { uint u; float f; } v; v.u = u << 16; return v.f; }
__device__ __forceinline__ ushort f2bf(float f) {   // RNE (weights / A2)
    union { float f; uint u; } v; v.f = f;
    uint r = v.u + 0x7fffu + ((v.u >> 16) & 1u);
    return (ushort)(r >> 16);
}
__device__ __forceinline__ uint pack2(float a, float b) { return (uint)f2bf(a) | ((uint)f2bf(b) << 16); }
// truncating bf16 pack of two floats in ONE v_perm_b32
__device__ __forceinline__ uint pack_trunc(float lo, float hi) {
    return __builtin_amdgcn_perm(__float_as_uint(hi), __float_as_uint(lo), 0x07060302u);
}
__device__ __forceinline__ float sigmoidf_(float x) { return 1.0f / (1.0f + expf(-x)); }
__device__ __forceinline__ float siluf_(float x)    { return x / (1.0f + expf(-x)); }

// Uniform cubic B-spline: the 4 possibly-nonzero values as polynomials of f = frac(u).
// b_{t0}=Ca, b_{t0-1}=Cb, b_{t0-2}=Cc, b_{t0-3}=Cd (t0=floor(u)); all others 0.
__device__ __forceinline__ void bs_coef(float f, float& Ca, float& Cb, float& Cc, float& Cd) {
    float f2 = f * f, f3 = f2 * f;
    Ca = f3 * (1.0f / 6.0f);
    Cb = (1.0f / 6.0f) + 0.5f * (f + f2 - f3);
    Cc = (2.0f / 3.0f) + 0.5f * f3 - f2;
    Cd = (1.0f / 6.0f) + 0.5f * (f2 - f) - f3 * (1.0f / 6.0f);
}

// ---------------- prep kernels ----------------

__global__ __launch_bounds__(256) void cvt_bf(const float* __restrict__ src, ushort* __restrict__ dst, int n8) {
    int t = blockIdx.x * 256 + threadIdx.x;
    if (t >= n8) return;
    const float4* s = (const float4*)src;
    float4 a = s[t * 2], b = s[t * 2 + 1];
    uint4 o; o.x = pack2(a.x, a.y); o.y = pack2(a.z, a.w); o.z = pack2(b.x, b.y); o.w = pack2(b.z, b.w);
    ((uint4*)dst)[t] = o;
}

__global__ __launch_bounds__(256) void copy_h_bf(const float* __restrict__ hp, ushort* __restrict__ comb) {
    int t = blockIdx.x * 256 + threadIdx.x;          // BATCH*512/8
    int b = t >> 6, j = (t & 63) * 8;
    const float4* s = (const float4*)(hp + (size_t)b * 512 + j);
    float4 a = s[0], c = s[1];
    uint4 o; o.x = pack2(a.x, a.y); o.y = pack2(a.z, a.w); o.z = pack2(c.x, c.y); o.w = pack2(c.z, c.w);
    *(uint4*)(comb + (size_t)b * 1024 + 512 + j) = o;
}

// w1aug, stored PRE-SWIZZLED: storage (n, k0, chunk_s, j) holds logical k = k0 + (chunk_s ^ ((n>>1)&3))*8 + j
// logical: k<1024 -> k1_base[n][k]; else k=1024+i*8+kk -> k1_spline[n][i][kk]*k1_scaler[n][i]
__global__ __launch_bounds__(256) void prep_w1aug(const float* __restrict__ k1b, const float* __restrict__ k1s,
                                                  const float* __restrict__ k1sc, ushort* __restrict__ w) {
    int t = blockIdx.x * 256 + threadIdx.x;
    if (t >= 64 * 9216) return;
    int n = t / 9216, r = t % 9216;
    int klog = (r & ~31) | ((((r >> 3) & 3) ^ ((n >> 1) & 3)) << 3) | (r & 7);
    float v;
    if (klog < 1024) v = k1b[n * 1024 + klog];
    else { int i = (klog - 1024) >> 3, k = (klog - 1024) & 7; v = k1s[(n * 1024 + i) * 8 + k] * k1sc[n * 1024 + i]; }
    w[t] = f2bf(v);
}

__global__ __launch_bounds__(256) void prep_w2aug(const float* __restrict__ k2b, const float* __restrict__ k2s,
                                                  const float* __restrict__ k2sc, ushort* __restrict__ w) {
    int t = blockIdx.x * 256 + threadIdx.x;
    if (t >= 512 * 576) return;
    int o = t / 576, c = t % 576;
    float v;
    if (c < 64) v = k2b[o * 64 + c];
    else { int i = (c - 64) >> 3, k = (c - 64) & 7; v = k2s[(o * 64 + i) * 8 + k] * k2sc[o * 64 + i]; }
    w[t] = f2bf(v);
}

__global__ __launch_bounds__(256) void prep_biasj(const float* __restrict__ ug_b, const float* __restrict__ rp_b,
                                                  float* __restrict__ bj) {
    int t = blockIdx.x * 256 + threadIdx.x;
    if (t < 512) bj[t] = ug_b[t];
    else if (t < 1024) bj[t] = rp_b[t - 512];
}

// ---------------- MFMA GEMM: C[m,n] (+)= A[m,:]·W[n,:]^T + bias[n] ----------------
template<bool ACCUM, bool BF16OUT, bool HASBIAS>
__global__ __launch_bounds__(256) void gemm_mfma(const ushort* __restrict__ A, int lda,
                                                 const ushort* __restrict__ Wt, int ldw,
                                                 const float* __restrict__ bias,
                                                 void* __restrict__ Cv, int ldc, int K) {
    __shared__ ushort As[128][32];
    __shared__ ushort Bs[128][32];
    const int tid = threadIdx.x;
    const int w = tid >> 6, lane = tid & 63;
    const int fr = lane & 15, fq = lane >> 4;
    const int m0 = blockIdx.x * 128, n0 = blockIdx.y * 128;
    const int wm = w & 1, wn = w >> 1;

    const int fa0 = (0 * 4 + w) * 512 + lane * 8;
    const int fa1 = (1 * 4 + w) * 512 + lane * 8;
    const ushort* gA0 = A  + (size_t)(m0 + fa0 / 32) * lda + (fa0 % 32);
    const ushort* gA1 = A  + (size_t)(m0 + fa1 / 32) * lda + (fa1 % 32);
    const ushort* gB0 = Wt + (size_t)(n0 + fa0 / 32) * ldw + (fa0 % 32);
    const ushort* gB1 = Wt + (size_t)(n0 + fa1 / 32) * ldw + (fa1 % 32);
    ushort* lA0 = &As[0][0] + (0 * 4 + w) * 512;
    ushort* lA1 = &As[0][0] + (1 * 4 + w) * 512;
    ushort* lB0 = &Bs[0][0] + (0 * 4 + w) * 512;
    ushort* lB1 = &Bs[0][0] + (1 * 4 + w) * 512;

    const ushort* aRd = &As[0][0] + (wm * 64 + fr) * 32 + fq * 8;
    const ushort* bRd = &Bs[0][0] + (wn * 64 + fr) * 32 + fq * 8;

    f32x4 acc[4][4] = {};
    for (int k0 = 0; k0 < K; k0 += 32) {
        gl_lds16(gA0, lA0); gl_lds16(gA1, lA1);
        gl_lds16(gB0, lB0); gl_lds16(gB1, lB1);
        gA0 += 32; gA1 += 32; gB0 += 32; gB1 += 32;
        __syncthreads();
        short8 af[4], bf[4];
#pragma unroll
        for (int mi = 0; mi < 4; ++mi) af[mi] = *(const short8*)(aRd + mi * 512);
#pragma unroll
        for (int ni = 0; ni < 4; ++ni) bf[ni] = *(const short8*)(bRd + ni * 512);
#pragma unroll
        for (int mi = 0; mi < 4; ++mi)
#pragma unroll
            for (int ni = 0; ni < 4; ++ni)
                acc[mi][ni] = __builtin_amdgcn_mfma_f32_16x16x32_bf16(af[mi], bf[ni], acc[mi][ni], 0, 0, 0);
        __syncthreads();
    }
#pragma unroll
    for (int mi = 0; mi < 4; ++mi) {
#pragma unroll
        for (int ni = 0; ni < 4; ++ni) {
            int n = n0 + wn * 64 + ni * 16 + fr;
            float bv = HASBIAS ? bias[n] : 0.0f;
#pragma unroll
            for (int r = 0; r < 4; ++r) {
                int m = m0 + wm * 64 + mi * 16 + fq * 4 + r;
                float val = acc[mi][ni][r] + bv;
                if (BF16OUT)      ((ushort*)Cv)[(size_t)m * ldc + n] = f2bf(val);
                else if (ACCUM)   ((float*)Cv)[(size_t)m * ldc + n] += val;
                else              ((float*)Cv)[(size_t)m * ldc + n] = val;
            }
        }
    }
}

// ---------------- KAN layer 1 via MFMA, split-K=4, swizzled LDS ----------------
__global__ __launch_bounds__(256) void kan1_mfma(const ushort* __restrict__ comb,   // [B][1024] bf16
                                                 const ushort* __restrict__ w1aug,  // [64][9216] bf16, pre-swizzled
                                                 const float* __restrict__ grid1,
                                                 float* __restrict__ midp) {
    __shared__ ushort As[64][32];
    __shared__ ushort Bs[64][32];
    const int tid = threadIdx.x;
    const int w = tid >> 6, lane = tid & 63;
    const int fr = lane & 15, fq = lane >> 4;
    const int m0 = blockIdx.x * 64;
    const int kb = blockIdx.y;
    const int kstart = kb * 2304;
    const float g0 = grid1[0];
    const float inv_h = 1.0f / (grid1[1] - g0);

    // B staging (linear dest; source layout pre-swizzled)
    const int fb = w * 512 + lane * 8;
    const ushort* gB = w1aug + (size_t)(fb >> 5) * 9216 + kstart + (fb & 31);
    ushort* lB = &Bs[0][0] + w * 512;

    // A staging: thread -> (srow 0..63, 16B chunk sq 0..3), XOR-swizzled chunk
    const int srow = tid >> 2, sq = tid & 3;
    const int psq = sq ^ ((srow >> 1) & 3);
    ushort* aWr = &As[srow][psq * 8];

    // frag reads: swizzled chunk (same for all ni since rows step by 16)
    const int cS = fq ^ ((fr >> 1) & 3);
    const ushort* aRd = &As[0][0] + (w * 16 + fr) * 32 + cS * 8;
    const ushort* bRd = &Bs[0][0] + fr * 32 + cS * 8;

    f32x4 acc[4] = {};
    for (int k0 = kstart; k0 < kstart + 2304; k0 += 32) {
        gl_lds16(gB, lB); gB += 32;
        uint4 o;
        if (k0 < 1024) {
            // silu region: 8 contiguous comb elems
            const ushort* src = comb + (size_t)(m0 + srow) * 1024 + k0 + sq * 8;
            uint4 raw = *(const uint4*)src;
            uint rr[4] = {raw.x, raw.y, raw.z, raw.w};
            uint oo[4];
#pragma unroll
            for (int p = 0; p < 4; ++p) {
                float lo = siluf_(bf2f(rr[p] & 0xffffu));
                float hi = siluf_(bf2f(rr[p] >> 16));
                oo[p] = pack_trunc(lo, hi);
            }
            o.x = oo[0]; o.y = oo[1]; o.z = oo[2]; o.w = oo[3];
        } else {
            // basis region: this thread owns input feature i (8 bases -> 4 packed words)
            int i = ((k0 - 1024) >> 3) + sq;
            float x = bf2f((uint)comb[(size_t)(m0 + srow) * 1024 + i]);
            float u = (x - g0) * inv_h;
            float fl = floorf(u);
            int t0 = (int)fl;
            float Ca, Cb_, Cc, Cd;
            bs_coef(u - fl, Ca, Cb_, Cc, Cd);
            uint ba = __float_as_uint(Ca) >> 16, bb = __float_as_uint(Cb_) >> 16;
            uint bc = __float_as_uint(Cc) >> 16, bd = __float_as_uint(Cd) >> 16;
            uint E0 = ba, E1 = bb | (ba << 16), E2 = bc | (bb << 16),
                 E3 = bd | (bc << 16), E4 = bd << 16;
            uint wd[4];
#pragma unroll
            for (int ww = 0; ww < 4; ++ww) {
                int d = t0 - 2 * ww;
                uint r = 0u;
                r = (d == 0) ? E0 : r;
                r = (d == 1) ? E1 : r;
                r = (d == 2) ? E2 : r;
                r = (d == 3) ? E3 : r;
                r = (d == 4) ? E4 : r;
                wd[ww] = r;
            }
            o.x = wd[0]; o.y = wd[1]; o.z = wd[2]; o.w = wd[3];
        }
        *(uint4*)aWr = o;
        __syncthreads();
        short8 af = *(const short8*)aRd;
#pragma unroll
        for (int ni = 0; ni < 4; ++ni) {
            short8 bv = *(const short8*)(bRd + ni * 512);
            acc[ni] = __builtin_amdgcn_mfma_f32_16x16x32_bf16(af, bv, acc[ni], 0, 0, 0);
        }
        __syncthreads();
    }
    float* outp = midp + (size_t)kb * (BATCH * 64);
#pragma unroll
    for (int ni = 0; ni < 4; ++ni)
#pragma unroll
        for (int r = 0; r < 4; ++r)
            outp[(size_t)(m0 + w * 16 + fq * 4 + r) * 64 + ni * 16 + fr] = acc[ni][r];
}

// ---------------- A2 = [silu(mid) | bases(mid)] bf16, summing 4 split-K partials ----------------
__global__ __launch_bounds__(256) void bs2_kernel(const float* __restrict__ midp,
                                                  const float* __restrict__ grid2,
                                                  ushort* __restrict__ A2) {
    int t = blockIdx.x * 256 + threadIdx.x;     // B*64
    if (t >= BATCH * 64) return;
    float x = midp[t] + midp[BATCH * 64 + t] + midp[2 * BATCH * 64 + t] + midp[3 * BATCH * 64 + t];
    int b = t >> 6, i = t & 63;
    float g0 = grid2[0], inv_h = 1.0f / (grid2[1] - g0);
    A2[(size_t)b * 576 + i] = f2bf(siluf_(x));
    float u = (x - g0) * inv_h;
    float fl = floorf(u);
    int t0 = (int)fl;
    float Ca, Cb_, Cc, Cd;
    bs_coef(u - fl, Ca, Cb_, Cc, Cd);
    uint4 o; uint wd[4];
#pragma unroll
    for (int ww = 0; ww < 4; ++ww) {
        int d = t0 - 2 * ww;
        float lo = (d == 0) ? Ca : (d == 1) ? Cb_ : (d == 2) ? Cc : (d == 3) ? Cd : 0.0f;
        float hi = (d == 1) ? Ca : (d == 2) ? Cb_ : (d == 3) ? Cc : (d == 4) ? Cd : 0.0f;
        wd[ww] = pack2(lo, hi);
    }
    o.x = wd[0]; o.y = wd[1]; o.z = wd[2]; o.w = wd[3];
    *(uint4*)&A2[(size_t)b * 576 + 64 + i * 8] = o;
}

// ---------------- fused gate + double-LN + blend ----------------
__device__ __forceinline__ void block_reduce_2(float& a, float& b, float (*red)[4]) {
#pragma unroll
    for (int off = 32; off; off >>= 1) {
        a += __shfl_xor(a, off, 64);
        b += __shfl_xor(b, off, 64);
    }
    int lane = threadIdx.x & 63, wid = threadIdx.x >> 6;
    if (lane == 0) { red[0][wid] = a; red[1][wid] = b; }
    __syncthreads();
    a = red[0][0] + red[0][1] + red[0][2] + red[0][3];
    b = red[1][0] + red[1][1] + red[1][2] + red[1][3];
}

// G row: [0:512) = ug_pre, [512:1024) = hc_pre. out = (1-u)*h_prev + u*silu(LN(LN(hc)))
__global__ __launch_bounds__(256) void final2(const float* __restrict__ G,
                                              const float* __restrict__ hprev,
                                              const float* __restrict__ ug_g,
                                              const float* __restrict__ ug_beta,
                                              const float* __restrict__ cg,
                                              const float* __restrict__ cb,
                                              float* __restrict__ out) {
    int row = blockIdx.x, tid = threadIdx.x;
    __shared__ float rA[2][4], rB[2][4], rC[2][4];
    const float* g = G + (size_t)row * 1024;
    float u0 = g[tid], u1 = g[tid + 256];
    float h0 = g[512 + tid], h1 = g[768 + tid];
    // LN(ug) -> sigmoid
    float s = u0 + u1, ss = u0 * u0 + u1 * u1;
    block_reduce_2(s, ss, rA);
    float mu = s * (1.0f / 512.0f);
    float var = ss * (1.0f / 512.0f) - mu * mu;
    float r = rsqrtf(var + 1e-5f);
    float uu0 = sigmoidf_((u0 - mu) * r * ug_g[tid] + ug_beta[tid]);
    float uu1 = sigmoidf_((u1 - mu) * r * ug_g[tid + 256] + ug_beta[tid + 256]);
    // LN(hc) with cn
    float cg0 = cg[tid], cg1 = cg[tid + 256], cb0 = cb[tid], cb1 = cb[tid + 256];
    float s2 = h0 + h1, ss2 = h0 * h0 + h1 * h1;
    block_reduce_2(s2, ss2, rB);
    float mu2 = s2 * (1.0f / 512.0f);
    float var2 = ss2 * (1.0f / 512.0f) - mu2 * mu2;
    float r2 = rsqrtf(var2 + 1e-5f);
    float w0 = (h0 - mu2) * r2 * cg0 + cb0;
    float w1 = (h1 - mu2) * r2 * cg1 + cb1;
    // LN again with cn, then silu
    float s3 = w0 + w1, ss3 = w0 * w0 + w1 * w1;
    block_reduce_2(s3, ss3, rC);
    float mu3 = s3 * (1.0f / 512.0f);
    float var3 = ss3 * (1.0f / 512.0f) - mu3 * mu3;
    float r3 = rsqrtf(var3 + 1e-5f);
    float c0 = siluf_((w0 - mu3) * r3 * cg0 + cb0);
    float c1 = siluf_((w1 - mu3) * r3 * cg1 + cb1);
    size_t o0 = (size_t)row * 512 + tid, o1 = o0 + 256;
    float hp0 = hprev[o0], hp1 = hprev[o1];
    out[o0] = (1.0f - uu0) * hp0 + uu0 * c0;
    out[o1] = (1.0f - uu1) * hp1 + uu1 * c1;
}

extern "C" void kernel_launch(void* const* d_in, const int* in_sizes, int n_in,
                              void* d_out, int out_size, void* d_ws, size_t ws_size,
                              hipStream_t stream) {
    const float* x        = (const float*)d_in[0];
    const float* h_prev   = (const float*)d_in[1];
    const float* ip_w     = (const float*)d_in[2];
    const float* ip_b     = (const float*)d_in[3];
    // d_in[4..7] rg_* : dead (reset gate unused in h_t)
    const float* ug_w     = (const float*)d_in[8];
    const float* ug_b     = (const float*)d_in[9];
    const float* ug_g     = (const float*)d_in[10];
    const float* ug_beta  = (const float*)d_in[11];
    const float* k1_base  = (const float*)d_in[12];
    const float* k1_spline= (const float*)d_in[13];
    const float* k1_scaler= (const float*)d_in[14];
    const float* grid1    = (const float*)d_in[15];
    const float* k2_base  = (const float*)d_in[16];
    const float* k2_spline= (const float*)d_in[17];
    const float* k2_scaler= (const float*)d_in[18];
    const float* grid2    = (const float*)d_in[19];
    const float* cn_g     = (const float*)d_in[20];
    const float* cn_b     = (const float*)d_in[21];
    const float* rp_w     = (const float*)d_in[22];
    const float* rp_b     = (const float*)d_in[23];
    float* out = (float*)d_out;
    char* W = (char*)d_ws;

    ushort* comb_bf = (ushort*)(W);                   // 33,554,432 B
    float*  G       = (float*) (W + 33554432);        // 67,108,864 B  (ug_pre | hc)
    float*  midp    = (float*) (W + 100663296);       // 16,777,216 B (4 split-K partials)
    ushort* x_bf    = (ushort*)(W + 100663296);       //  aliases midp (dead before kan1)
    ushort* A2_bf   = (ushort*)(W + 117440512);       // 18,874,368 B
    ushort* ipw_bf  = (ushort*)(W + 136314880);       //    262,144 B
    ushort* wjoint  = (ushort*)(W + 136577024);       //  2,097,152 B (ug_w rows 0-511, rp_w rows 512-1023)
    ushort* w1aug   = (ushort*)(W + 138674176);       //  1,179,648 B (pre-swizzled)
    ushort* w2aug   = (ushort*)(W + 139853824);       //    589,824 B
    float*  biasj   = (float*) (W + 140443648);       //      4,096 B

    // --- prep ---
    hipLaunchKernelGGL(cvt_bf, dim3(2048), dim3(256), 0, stream, x, x_bf, BATCH * 256 / 8);
    hipLaunchKernelGGL(cvt_bf, dim3(64),   dim3(256), 0, stream, ip_w, ipw_bf, 512 * 256 / 8);
    hipLaunchKernelGGL(cvt_bf, dim3(256),  dim3(256), 0, stream, ug_w, wjoint, 512 * 1024 / 8);
    hipLaunchKernelGGL(cvt_bf, dim3(256),  dim3(256), 0, stream, rp_w, wjoint + 512 * 1024, 512 * 1024 / 8);
    hipLaunchKernelGGL(prep_biasj, dim3(4), dim3(256), 0, stream, ug_b, rp_b, biasj);
    hipLaunchKernelGGL(prep_w1aug, dim3(2304), dim3(256), 0, stream, k1_base, k1_spline, k1_scaler, w1aug);
    hipLaunchKernelGGL(prep_w2aug, dim3(1152), dim3(256), 0, stream, k2_base, k2_spline, k2_scaler, w2aug);
    hipLaunchKernelGGL(copy_h_bf, dim3(4096), dim3(256), 0, stream, h_prev, comb_bf);

    // --- combined[:, :512] = bf16(x @ ip_w.T + ip_b) ---
    hipLaunchKernelGGL((gemm_mfma<false, true, true>), dim3(BATCH / 128, 4), dim3(256), 0, stream,
                       x_bf, 256, ipw_bf, 256, ip_b, comb_bf, 1024, 256);

    // --- joint GEMM: G[:, 0:512] = ug_pre, G[:, 512:1024] = residual ---
    hipLaunchKernelGGL((gemm_mfma<false, false, true>), dim3(BATCH / 128, 8), dim3(256), 0, stream,
                       comb_bf, 1024, wjoint, 1024, biasj, G, 1024, 1024);

    // --- KAN1 (split-K=4) -> midp partials -> A2 ---
    hipLaunchKernelGGL(kan1_mfma, dim3(BATCH / 64, 4), dim3(256), 0, stream, comb_bf, w1aug, grid1, midp);
    hipLaunchKernelGGL(bs2_kernel, dim3(BATCH * 64 / 256), dim3(256), 0, stream, midp, grid2, A2_bf);

    // --- KAN2 accumulated onto residual half of G ---
    hipLaunchKernelGGL((gemm_mfma<true, false, false>), dim3(BATCH / 128, 4), dim3(256), 0, stream,
                       A2_bf, 576, w2aug, 576, (const float*)nullptr, (void*)(G + 512), 1024, 576);

    // --- h_t ---
    hipLaunchKernelGGL(final2, dim3(BATCH), dim3(256), 0, stream, G, h_prev, ug_g, ug_beta, cn_g, cn_b, out);
}

// Round 4
// 209.741 us; speedup vs baseline: 7.1204x; 1.1399x over previous
//
#include <hip/hip_runtime.h>
#include <hip/hip_bf16.h>

#define BATCH 16384

typedef __attribute__((ext_vector_type(8))) short short8;
typedef __attribute__((ext_vector_type(4))) float f32x4;

typedef const __attribute__((address_space(1))) uint* gas_t;
typedef __attribute__((address_space(3))) uint* las_t;

__device__ __forceinline__ void gl_lds16(const void* g, void* l) {
    __builtin_amdgcn_global_load_lds((gas_t)g, (las_t)l, 16, 0, 0);
}

__device__ __forceinline__ float bf2f(uint u) { union { uint u; float f; } v; v.u = u << 16; return v.f; }
__device__ __forceinline__ ushort f2bf(float f) {   // RNE
    union { float f; uint u; } v; v.f = f;
    uint r = v.u + 0x7fffu + ((v.u >> 16) & 1u);
    return (ushort)(r >> 16);
}
__device__ __forceinline__ uint pack2(float a, float b) { return (uint)f2bf(a) | ((uint)f2bf(b) << 16); }
// truncating bf16 pack of two floats in ONE v_perm_b32
__device__ __forceinline__ uint pack_trunc(float lo, float hi) {
    return __builtin_amdgcn_perm(__float_as_uint(hi), __float_as_uint(lo), 0x07060302u);
}
// fast activations: v_exp_f32 + v_rcp_f32 (1-ulp class; fine vs bf16 threshold)
__device__ __forceinline__ float sigmoidf_(float x) { return __builtin_amdgcn_rcpf(1.0f + __expf(-x)); }
__device__ __forceinline__ float siluf_(float x)    { return x * sigmoidf_(x); }

// Uniform cubic B-spline: 8 packed bf16 bases via 128-bit funnel-shift placement.
// b_t = N(u-t); nonzero only for t in [t0-3, t0]; values (Cd,Cc,Cb,Ca) placed at halfword t0-3.
__device__ __forceinline__ void bases_packed(float x, float g0, float inv_h, uint o[4]) {
    float u = (x - g0) * inv_h;
    float fl = floorf(u);
    float f = u - fl;
    float f2 = f * f, f3 = f2 * f;
    float Ca = f3 * (1.0f / 6.0f);
    float Cb = (1.0f / 6.0f) + 0.5f * (f + f2 - f3);
    float Cc = (2.0f / 3.0f) + 0.5f * f3 - f2;
    float Cd = (1.0f / 6.0f) + 0.5f * (f2 - f) - f3 * (1.0f / 6.0f);
    int t0 = (int)fl;
    t0 = max(-8, min(t0, 19));                       // keep shift arithmetic sane
    uint dlo = pack_trunc(Cd, Cc);
    uint dhi = pack_trunc(Cb, Ca);
    unsigned long long D = (unsigned long long)dlo | ((unsigned long long)dhi << 32);
    int sp = t0 * 16 - 48;
    unsigned long long l1 = D << (sp & 63);
    unsigned long long r1 = D >> ((-sp) & 63);
    unsigned long long r2 = D >> ((64 - sp) & 63);
    unsigned long long l2 = D << ((sp - 64) & 63);
    unsigned long long lo = (sp >= 0) ? (sp < 64 ? l1 : 0ull) : (sp > -64 ? r1 : 0ull);
    unsigned long long hi = (sp > 0 && sp < 128) ? (sp < 64 ? r2 : l2) : 0ull;
    o[0] = (uint)lo; o[1] = (uint)(lo >> 32); o[2] = (uint)hi; o[3] = (uint)(hi >> 32);
}

// ---------------- prep kernels ----------------

__global__ __launch_bounds__(256) void cvt_bf(const float* __restrict__ src, ushort* __restrict__ dst, int n8) {
    int t = blockIdx.x * 256 + threadIdx.x;
    if (t >= n8) return;
    const float4* s = (const float4*)src;
    float4 a = s[t * 2], b = s[t * 2 + 1];
    uint4 o; o.x = pack2(a.x, a.y); o.y = pack2(a.z, a.w); o.z = pack2(b.x, b.y); o.w = pack2(b.z, b.w);
    ((uint4*)dst)[t] = o;
}

__global__ __launch_bounds__(256) void copy_h_bf(const float* __restrict__ hp, ushort* __restrict__ comb) {
    int t = blockIdx.x * 256 + threadIdx.x;          // BATCH*512/8
    int b = t >> 6, j = (t & 63) * 8;
    const float4* s = (const float4*)(hp + (size_t)b * 512 + j);
    float4 a = s[0], c = s[1];
    uint4 o; o.x = pack2(a.x, a.y); o.y = pack2(a.z, a.w); o.z = pack2(c.x, c.y); o.w = pack2(c.z, c.w);
    *(uint4*)(comb + (size_t)b * 1024 + 512 + j) = o;
}

// w1aug storage pre-swizzled for the kan1 BK=64 layout:
// storage (n, r) with r = step*64 + pc*8 + j holds logical k = step*64 + ((pc ^ (n&7)))*8 + j
__global__ __launch_bounds__(256) void prep_w1aug(const float* __restrict__ k1b, const float* __restrict__ k1s,
                                                  const float* __restrict__ k1sc, ushort* __restrict__ w) {
    int t = blockIdx.x * 256 + threadIdx.x;
    if (t >= 64 * 9216) return;
    int n = t / 9216, r = t % 9216;
    int klog = (r & ~63) | ((((r >> 3) & 7) ^ (n & 7)) << 3) | (r & 7);
    float v;
    if (klog < 1024) v = k1b[n * 1024 + klog];
    else { int i = (klog - 1024) >> 3, k = (klog - 1024) & 7; v = k1s[(n * 1024 + i) * 8 + k] * k1sc[n * 1024 + i]; }
    w[t] = f2bf(v);
}

__global__ __launch_bounds__(256) void prep_w2aug(const float* __restrict__ k2b, const float* __restrict__ k2s,
                                                  const float* __restrict__ k2sc, ushort* __restrict__ w) {
    int t = blockIdx.x * 256 + threadIdx.x;
    if (t >= 512 * 576) return;
    int o = t / 576, c = t % 576;
    float v;
    if (c < 64) v = k2b[o * 64 + c];
    else { int i = (c - 64) >> 3, k = (c - 64) & 7; v = k2s[(o * 64 + i) * 8 + k] * k2sc[o * 64 + i]; }
    w[t] = f2bf(v);
}

__global__ __launch_bounds__(256) void prep_biasj(const float* __restrict__ ug_b, const float* __restrict__ rp_b,
                                                  float* __restrict__ bj) {
    int t = blockIdx.x * 256 + threadIdx.x;
    if (t < 512) bj[t] = ug_b[t];
    else if (t < 1024) bj[t] = rp_b[t - 512];
}

// ---------------- MFMA GEMM, 2-phase double-buffered (T3-minimum) ----------------
// C[m,n] (+)= A[m,:]·W[n,:]^T + bias[n]. 128x128 tile, BK=32, 4 waves.
template<bool ACCUM, bool BF16OUT, bool HASBIAS>
__global__ __launch_bounds__(256) void gemm_mfma(const ushort* __restrict__ A, int lda,
                                                 const ushort* __restrict__ Wt, int ldw,
                                                 const float* __restrict__ bias,
                                                 void* __restrict__ Cv, int ldc, int K) {
    __shared__ ushort As[2][128 * 32];
    __shared__ ushort Bs[2][128 * 32];
    const int tid = threadIdx.x;
    const int w = tid >> 6, lane = tid & 63;
    const int fr = lane & 15, fq = lane >> 4;
    const int m0 = blockIdx.x * 128, n0 = blockIdx.y * 128;
    const int wm = w & 1, wn = w >> 1;

    const int fa0 = w * 512 + lane * 8;
    const int fa1 = (4 + w) * 512 + lane * 8;
    const ushort* gA0 = A  + (size_t)(m0 + fa0 / 32) * lda + (fa0 % 32);
    const ushort* gA1 = A  + (size_t)(m0 + fa1 / 32) * lda + (fa1 % 32);
    const ushort* gB0 = Wt + (size_t)(n0 + fa0 / 32) * ldw + (fa0 % 32);
    const ushort* gB1 = Wt + (size_t)(n0 + fa1 / 32) * ldw + (fa1 % 32);

    const int nt = K / 32;
    // prologue: stage tile 0 into buffer 0
    gl_lds16(gA0, &As[0][fa0]); gl_lds16(gA1, &As[0][fa1]);
    gl_lds16(gB0, &Bs[0][fa0]); gl_lds16(gB1, &Bs[0][fa1]);
    gA0 += 32; gA1 += 32; gB0 += 32; gB1 += 32;

    f32x4 acc[4][4] = {};
    int cur = 0;
    for (int t = 0; t < nt; ++t) {
        __syncthreads();                 // buf[cur] ready (compiler drains vmcnt before barrier)
        if (t + 1 < nt) {                // issue next tile while MFMA runs
            gl_lds16(gA0, &As[cur ^ 1][fa0]); gl_lds16(gA1, &As[cur ^ 1][fa1]);
            gl_lds16(gB0, &Bs[cur ^ 1][fa0]); gl_lds16(gB1, &Bs[cur ^ 1][fa1]);
            gA0 += 32; gA1 += 32; gB0 += 32; gB1 += 32;
        }
        const ushort* aRd = &As[cur][0] + (wm * 64 + fr) * 32 + fq * 8;
        const ushort* bRd = &Bs[cur][0] + (wn * 64 + fr) * 32 + fq * 8;
        short8 af[4], bf[4];
#pragma unroll
        for (int mi = 0; mi < 4; ++mi) af[mi] = *(const short8*)(aRd + mi * 512);
#pragma unroll
        for (int ni = 0; ni < 4; ++ni) bf[ni] = *(const short8*)(bRd + ni * 512);
#pragma unroll
        for (int mi = 0; mi < 4; ++mi)
#pragma unroll
            for (int ni = 0; ni < 4; ++ni)
                acc[mi][ni] = __builtin_amdgcn_mfma_f32_16x16x32_bf16(af[mi], bf[ni], acc[mi][ni], 0, 0, 0);
        cur ^= 1;
    }
#pragma unroll
    for (int mi = 0; mi < 4; ++mi) {
#pragma unroll
        for (int ni = 0; ni < 4; ++ni) {
            int n = n0 + wn * 64 + ni * 16 + fr;
            float bv = HASBIAS ? bias[n] : 0.0f;
#pragma unroll
            for (int r = 0; r < 4; ++r) {
                int m = m0 + wm * 64 + mi * 16 + fq * 4 + r;
                float val = acc[mi][ni][r] + bv;
                if (BF16OUT)      ((ushort*)Cv)[(size_t)m * ldc + n] = f2bf(val);
                else if (ACCUM)   ((float*)Cv)[(size_t)m * ldc + n] += val;
                else              ((float*)Cv)[(size_t)m * ldc + n] = val;
            }
        }
    }
}

// ---------------- KAN layer 1: 32-row blocks, BK=64, split-K=4, swizzled LDS ----------------
__global__ __launch_bounds__(256) void kan1_mfma(const ushort* __restrict__ comb,   // [B][1024] bf16
                                                 const ushort* __restrict__ w1aug,  // [64][9216] bf16, pre-swizzled
                                                 const float* __restrict__ grid1,
                                                 float* __restrict__ midp) {
    __shared__ ushort As[32 * 64];   // 4 KB, row stride 64 (128B), 16B chunk pc = c ^ (row&7)
    __shared__ ushort Bs[64 * 64];   // 8 KB, same swizzle (pre-baked in w1aug)
    const int tid = threadIdx.x;
    const int w = tid >> 6, lane = tid & 63;
    const int fr = lane & 15, fq = lane >> 4;
    const int m0 = blockIdx.x * 32;
    const int kb = blockIdx.y;
    const int kstart = kb * 2304;
    const float g0 = grid1[0];
    const float inv_h = 1.0f / (grid1[1] - g0);

    // A staging: one 16B chunk per thread
    const int srow = tid >> 3, sc = tid & 7;
    ushort* aWr = As + srow * 64 + ((sc ^ (srow & 7)) << 3);
    const ushort* combRow = comb + (size_t)(m0 + srow) * 1024;

    // B staging: 2 linear gl_lds per thread (source pre-swizzled)
    const int bn = tid >> 3, bpc = tid & 7;
    const ushort* gB0 = w1aug + (size_t)bn * 9216 + kstart + bpc * 8;
    const ushort* gB1 = w1aug + (size_t)(bn + 32) * 9216 + kstart + bpc * 8;
    ushort* lB0 = Bs + tid * 8;
    ushort* lB1 = Bs + 2048 + tid * 8;

    const int wm = w & 1, wn = w >> 1;
    const int arow = wm * 16 + fr;
    const ushort* aRd = As + arow * 64;
    const int axor = arow & 7;

    f32x4 acc[2] = {};
    for (int step = 0; step < 36; ++step) {
        const int k0 = kstart + step * 64;
        gl_lds16(gB0, lB0); gl_lds16(gB1, lB1);
        gB0 += 64; gB1 += 64;
        uint o[4];
        if (k0 < 1024) {
            uint4 raw = *(const uint4*)(combRow + k0 + sc * 8);
            uint rr[4] = {raw.x, raw.y, raw.z, raw.w};
#pragma unroll
            for (int p = 0; p < 4; ++p) {
                float loF = siluf_(bf2f(rr[p] & 0xffffu));
                float hiF = siluf_(bf2f(rr[p] >> 16));
                o[p] = pack_trunc(loF, hiF);
            }
        } else {
            int i = ((k0 - 1024) >> 3) + sc;
            float x = bf2f((uint)combRow[i]);
            bases_packed(x, g0, inv_h, o);
        }
        uint4 o4; o4.x = o[0]; o4.y = o[1]; o4.z = o[2]; o4.w = o[3];
        *(uint4*)aWr = o4;
        __syncthreads();
#pragma unroll
        for (int s = 0; s < 2; ++s) {
            short8 af = *(const short8*)(aRd + (((s * 4 + fq) ^ axor) << 3));
#pragma unroll
            for (int ni = 0; ni < 2; ++ni) {
                int n = wn * 32 + ni * 16 + fr;
                short8 bv = *(const short8*)(Bs + n * 64 + (((s * 4 + fq) ^ (n & 7)) << 3));
                acc[ni] = __builtin_amdgcn_mfma_f32_16x16x32_bf16(af, bv, acc[ni], 0, 0, 0);
            }
        }
        __syncthreads();
    }
    float* outp = midp + (size_t)kb * (BATCH * 64);
#pragma unroll
    for (int ni = 0; ni < 2; ++ni)
#pragma unroll
        for (int r = 0; r < 4; ++r)
            outp[(size_t)(m0 + wm * 16 + fq * 4 + r) * 64 + wn * 32 + ni * 16 + fr] = acc[ni][r];
}

// ---------------- A2 = [silu(mid) | bases(mid)] bf16, summing 4 split-K partials ----------------
__global__ __launch_bounds__(256) void bs2_kernel(const float* __restrict__ midp,
                                                  const float* __restrict__ grid2,
                                                  ushort* __restrict__ A2) {
    int t = blockIdx.x * 256 + threadIdx.x;     // B*64
    if (t >= BATCH * 64) return;
    float x = midp[t] + midp[BATCH * 64 + t] + midp[2 * BATCH * 64 + t] + midp[3 * BATCH * 64 + t];
    int b = t >> 6, i = t & 63;
    float g0 = grid2[0], inv_h = 1.0f / (grid2[1] - g0);
    A2[(size_t)b * 576 + i] = f2bf(siluf_(x));
    uint o[4];
    bases_packed(x, g0, inv_h, o);
    uint4 o4; o4.x = o[0]; o4.y = o[1]; o4.z = o[2]; o4.w = o[3];
    *(uint4*)&A2[(size_t)b * 576 + 64 + i * 8] = o4;
}

// ---------------- fused gate + double-LN + blend ----------------
__device__ __forceinline__ void block_reduce_2(float& a, float& b, float (*red)[4]) {
#pragma unroll
    for (int off = 32; off; off >>= 1) {
        a += __shfl_xor(a, off, 64);
        b += __shfl_xor(b, off, 64);
    }
    int lane = threadIdx.x & 63, wid = threadIdx.x >> 6;
    if (lane == 0) { red[0][wid] = a; red[1][wid] = b; }
    __syncthreads();
    a = red[0][0] + red[0][1] + red[0][2] + red[0][3];
    b = red[1][0] + red[1][1] + red[1][2] + red[1][3];
}

// G row: [0:512) = ug_pre, [512:1024) = hc_pre. out = (1-u)*h_prev + u*silu(LN(LN(hc)))
__global__ __launch_bounds__(256) void final2(const float* __restrict__ G,
                                              const float* __restrict__ hprev,
                                              const float* __restrict__ ug_g,
                                              const float* __restrict__ ug_beta,
                                              const float* __restrict__ cg,
                                              const float* __restrict__ cb,
                                              float* __restrict__ out) {
    int row = blockIdx.x, tid = threadIdx.x;
    __shared__ float rA[2][4], rB[2][4], rC[2][4];
    const float* g = G + (size_t)row * 1024;
    float u0 = g[tid], u1 = g[tid + 256];
    float h0 = g[512 + tid], h1 = g[768 + tid];
    float s = u0 + u1, ss = u0 * u0 + u1 * u1;
    block_reduce_2(s, ss, rA);
    float mu = s * (1.0f / 512.0f);
    float var = ss * (1.0f / 512.0f) - mu * mu;
    float r = rsqrtf(var + 1e-5f);
    float uu0 = sigmoidf_((u0 - mu) * r * ug_g[tid] + ug_beta[tid]);
    float uu1 = sigmoidf_((u1 - mu) * r * ug_g[tid + 256] + ug_beta[tid + 256]);
    float cg0 = cg[tid], cg1 = cg[tid + 256], cb0 = cb[tid], cb1 = cb[tid + 256];
    float s2 = h0 + h1, ss2 = h0 * h0 + h1 * h1;
    block_reduce_2(s2, ss2, rB);
    float mu2 = s2 * (1.0f / 512.0f);
    float var2 = ss2 * (1.0f / 512.0f) - mu2 * mu2;
    float r2 = rsqrtf(var2 + 1e-5f);
    float w0 = (h0 - mu2) * r2 * cg0 + cb0;
    float w1 = (h1 - mu2) * r2 * cg1 + cb1;
    float s3 = w0 + w1, ss3 = w0 * w0 + w1 * w1;
    block_reduce_2(s3, ss3, rC);
    float mu3 = s3 * (1.0f / 512.0f);
    float var3 = ss3 * (1.0f / 512.0f) - mu3 * mu3;
    float r3 = rsqrtf(var3 + 1e-5f);
    float c0 = siluf_((w0 - mu3) * r3 * cg0 + cb0);
    float c1 = siluf_((w1 - mu3) * r3 * cg1 + cb1);
    size_t o0 = (size_t)row * 512 + tid, o1 = o0 + 256;
    float hp0 = hprev[o0], hp1 = hprev[o1];
    out[o0] = (1.0f - uu0) * hp0 + uu0 * c0;
    out[o1] = (1.0f - uu1) * hp1 + uu1 * c1;
}

extern "C" void kernel_launch(void* const* d_in, const int* in_sizes, int n_in,
                              void* d_out, int out_size, void* d_ws, size_t ws_size,
                              hipStream_t stream) {
    const float* x        = (const float*)d_in[0];
    const float* h_prev   = (const float*)d_in[1];
    const float* ip_w     = (const float*)d_in[2];
    const float* ip_b     = (const float*)d_in[3];
    // d_in[4..7] rg_* : dead (reset gate unused in h_t)
    const float* ug_w     = (const float*)d_in[8];
    const float* ug_b     = (const float*)d_in[9];
    const float* ug_g     = (const float*)d_in[10];
    const float* ug_beta  = (const float*)d_in[11];
    const float* k1_base  = (const float*)d_in[12];
    const float* k1_spline= (const float*)d_in[13];
    const float* k1_scaler= (const float*)d_in[14];
    const float* grid1    = (const float*)d_in[15];
    const float* k2_base  = (const float*)d_in[16];
    const float* k2_spline= (const float*)d_in[17];
    const float* k2_scaler= (const float*)d_in[18];
    const float* grid2    = (const float*)d_in[19];
    const float* cn_g     = (const float*)d_in[20];
    const float* cn_b     = (const float*)d_in[21];
    const float* rp_w     = (const float*)d_in[22];
    const float* rp_b     = (const float*)d_in[23];
    float* out = (float*)d_out;
    char* W = (char*)d_ws;

    ushort* comb_bf = (ushort*)(W);                   // 33,554,432 B
    float*  G       = (float*) (W + 33554432);        // 67,108,864 B  (ug_pre | hc)
    float*  midp    = (float*) (W + 100663296);       // 16,777,216 B (4 split-K partials)
    ushort* x_bf    = (ushort*)(W + 100663296);       //  aliases midp (dead before kan1)
    ushort* A2_bf   = (ushort*)(W + 117440512);       // 18,874,368 B
    ushort* ipw_bf  = (ushort*)(W + 136314880);       //    262,144 B
    ushort* wjoint  = (ushort*)(W + 136577024);       //  2,097,152 B (ug_w rows 0-511, rp_w rows 512-1023)
    ushort* w1aug   = (ushort*)(W + 138674176);       //  1,179,648 B (pre-swizzled)
    ushort* w2aug   = (ushort*)(W + 139853824);       //    589,824 B
    float*  biasj   = (float*) (W + 140443648);       //      4,096 B

    // --- prep ---
    hipLaunchKernelGGL(cvt_bf, dim3(2048), dim3(256), 0, stream, x, x_bf, BATCH * 256 / 8);
    hipLaunchKernelGGL(cvt_bf, dim3(64),   dim3(256), 0, stream, ip_w, ipw_bf, 512 * 256 / 8);
    hipLaunchKernelGGL(cvt_bf, dim3(256),  dim3(256), 0, stream, ug_w, wjoint, 512 * 1024 / 8);
    hipLaunchKernelGGL(cvt_bf, dim3(256),  dim3(256), 0, stream, rp_w, wjoint + 512 * 1024, 512 * 1024 / 8);
    hipLaunchKernelGGL(prep_biasj, dim3(4), dim3(256), 0, stream, ug_b, rp_b, biasj);
    hipLaunchKernelGGL(prep_w1aug, dim3(2304), dim3(256), 0, stream, k1_base, k1_spline, k1_scaler, w1aug);
    hipLaunchKernelGGL(prep_w2aug, dim3(1152), dim3(256), 0, stream, k2_base, k2_spline, k2_scaler, w2aug);
    hipLaunchKernelGGL(copy_h_bf, dim3(4096), dim3(256), 0, stream, h_prev, comb_bf);

    // --- combined[:, :512] = bf16(x @ ip_w.T + ip_b) ---
    hipLaunchKernelGGL((gemm_mfma<false, true, true>), dim3(BATCH / 128, 4), dim3(256), 0, stream,
                       x_bf, 256, ipw_bf, 256, ip_b, comb_bf, 1024, 256);

    // --- joint GEMM: G[:, 0:512] = ug_pre, G[:, 512:1024] = residual ---
    hipLaunchKernelGGL((gemm_mfma<false, false, true>), dim3(BATCH / 128, 8), dim3(256), 0, stream,
                       comb_bf, 1024, wjoint, 1024, biasj, G, 1024, 1024);

    // --- KAN1 (32-row blocks, split-K=4) -> midp partials -> A2 ---
    hipLaunchKernelGGL(kan1_mfma, dim3(BATCH / 32, 4), dim3(256), 0, stream, comb_bf, w1aug, grid1, midp);
    hipLaunchKernelGGL(bs2_kernel, dim3(BATCH * 64 / 256), dim3(256), 0, stream, midp, grid2, A2_bf);

    // --- KAN2 accumulated onto residual half of G ---
    hipLaunchKernelGGL((gemm_mfma<true, false, false>), dim3(BATCH / 128, 4), dim3(256), 0, stream,
                       A2_bf, 576, w2aug, 576, (const float*)nullptr, (void*)(G + 512), 1024, 576);

    // --- h_t ---
    hipLaunchKernelGGL(final2, dim3(BATCH), dim3(256), 0, stream, G, h_prev, ug_g, ug_beta, cn_g, cn_b, out);
}

// Round 5
// 173.379 us; speedup vs baseline: 8.6138x; 1.2097x over previous
//
#include <hip/hip_runtime.h>
#include <hip/hip_bf16.h>

#define BATCH 16384

typedef __attribute__((ext_vector_type(8))) short short8;
typedef __attribute__((ext_vector_type(4))) float f32x4;

typedef const __attribute__((address_space(1))) uint* gas_t;
typedef __attribute__((address_space(3))) uint* las_t;

__device__ __forceinline__ void gl_lds16(const void* g, void* l) {
    __builtin_amdgcn_global_load_lds((gas_t)g, (las_t)l, 16, 0, 0);
}

__device__ __forceinline__ float bf2f(uint u) { union { uint u; float f; } v; v.u = u << 16; return v.f; }
__device__ __forceinline__ ushort f2bf(float f) {   // RNE
    union { float f; uint u; } v; v.f = f;
    uint r = v.u + 0x7fffu + ((v.u >> 16) & 1u);
    return (ushort)(r >> 16);
}
__device__ __forceinline__ uint pack2(float a, float b) { return (uint)f2bf(a) | ((uint)f2bf(b) << 16); }
// truncating bf16 pack of two floats in ONE v_perm_b32
__device__ __forceinline__ uint pack_trunc(float lo, float hi) {
    return __builtin_amdgcn_perm(__float_as_uint(hi), __float_as_uint(lo), 0x07060302u);
}
// fast activations: v_exp_f32 + v_rcp_f32
__device__ __forceinline__ float sigmoidf_(float x) { return __builtin_amdgcn_rcpf(1.0f + __expf(-x)); }
__device__ __forceinline__ float siluf_(float x)    { return x * sigmoidf_(x); }

// Uniform cubic B-spline: 8 packed bf16 bases via 128-bit funnel-shift placement.
__device__ __forceinline__ void bases_packed(float x, float g0, float inv_h, uint o[4]) {
    float u = (x - g0) * inv_h;
    float fl = floorf(u);
    float f = u - fl;
    float f2 = f * f, f3 = f2 * f;
    float Ca = f3 * (1.0f / 6.0f);
    float Cb = (1.0f / 6.0f) + 0.5f * (f + f2 - f3);
    float Cc = (2.0f / 3.0f) + 0.5f * f3 - f2;
    float Cd = (1.0f / 6.0f) + 0.5f * (f2 - f) - f3 * (1.0f / 6.0f);
    int t0 = (int)fl;
    t0 = max(-8, min(t0, 19));
    uint dlo = pack_trunc(Cd, Cc);
    uint dhi = pack_trunc(Cb, Ca);
    unsigned long long D = (unsigned long long)dlo | ((unsigned long long)dhi << 32);
    int sp = t0 * 16 - 48;
    unsigned long long l1 = D << (sp & 63);
    unsigned long long r1 = D >> ((-sp) & 63);
    unsigned long long r2 = D >> ((64 - sp) & 63);
    unsigned long long l2 = D << ((sp - 64) & 63);
    unsigned long long lo = (sp >= 0) ? (sp < 64 ? l1 : 0ull) : (sp > -64 ? r1 : 0ull);
    unsigned long long hi = (sp > 0 && sp < 128) ? (sp < 64 ? r2 : l2) : 0ull;
    o[0] = (uint)lo; o[1] = (uint)(lo >> 32); o[2] = (uint)hi; o[3] = (uint)(hi >> 32);
}

// ---------------- prep kernels ----------------

__global__ __launch_bounds__(256) void cvt_bf(const float* __restrict__ src, ushort* __restrict__ dst, int n8) {
    int t = blockIdx.x * 256 + threadIdx.x;
    if (t >= n8) return;
    const float4* s = (const float4*)src;
    float4 a = s[t * 2], b = s[t * 2 + 1];
    uint4 o; o.x = pack2(a.x, a.y); o.y = pack2(a.z, a.w); o.z = pack2(b.x, b.y); o.w = pack2(b.z, b.w);
    ((uint4*)dst)[t] = o;
}

// Acat[:, 512:1024] = bf16(h_prev); Acat row stride 1600
__global__ __launch_bounds__(256) void copy_h_bf(const float* __restrict__ hp, ushort* __restrict__ acat) {
    int t = blockIdx.x * 256 + threadIdx.x;          // BATCH*512/8
    int b = t >> 6, j = (t & 63) * 8;
    const float4* s = (const float4*)(hp + (size_t)b * 512 + j);
    float4 a = s[0], c = s[1];
    uint4 o; o.x = pack2(a.x, a.y); o.y = pack2(a.z, a.w); o.z = pack2(c.x, c.y); o.w = pack2(c.z, c.w);
    *(uint4*)(acat + (size_t)b * 1600 + 512 + j) = o;
}

// w1aug storage pre-swizzled for kan1 BK=64: storage (n, step*64 + pc*8 + j) holds
// logical k = step*64 + (pc ^ (n&7))*8 + j
__global__ __launch_bounds__(256) void prep_w1aug(const float* __restrict__ k1b, const float* __restrict__ k1s,
                                                  const float* __restrict__ k1sc, ushort* __restrict__ w) {
    int t = blockIdx.x * 256 + threadIdx.x;
    if (t >= 64 * 9216) return;
    int n = t / 9216, r = t % 9216;
    int klog = (r & ~63) | ((((r >> 3) & 7) ^ (n & 7)) << 3) | (r & 7);
    float v;
    if (klog < 1024) v = k1b[n * 1024 + klog];
    else { int i = (klog - 1024) >> 3, k = (klog - 1024) & 7; v = k1s[(n * 1024 + i) * 8 + k] * k1sc[n * 1024 + i]; }
    w[t] = f2bf(v);
}

// Wcat[n][0:1024)=rp_w; [1024:1088)=k2_base; [1088+i*8+k]=k2_spline*scaler
__global__ __launch_bounds__(256) void prep_wcat(const float* __restrict__ rp, const float* __restrict__ k2b,
                                                 const float* __restrict__ k2s, const float* __restrict__ k2sc,
                                                 ushort* __restrict__ w) {
    int t = blockIdx.x * 256 + threadIdx.x;
    if (t >= 512 * 1600) return;
    int n = t / 1600, c = t % 1600;
    float v;
    if (c < 1024) v = rp[n * 1024 + c];
    else if (c < 1088) v = k2b[n * 64 + (c - 1024)];
    else { int i = (c - 1088) >> 3, k = (c - 1088) & 7; v = k2s[(n * 64 + i) * 8 + k] * k2sc[n * 64 + i]; }
    w[t] = f2bf(v);
}

// ---------------- MFMA GEMM: C[m,n] = bf16(A[m,:]·W[n,:]^T + bias[n]) ----------------
// 128x128 tile, BK=64, double-buffered, XOR-swizzled LDS (storage chunk = logical ^ (row&7)).
__global__ __launch_bounds__(256) void gemm_mfma(const ushort* __restrict__ A, int lda,
                                                 const ushort* __restrict__ Wt, int ldw,
                                                 const float* __restrict__ bias,
                                                 ushort* __restrict__ C, int ldc, int K) {
    __shared__ ushort As[2][128 * 64];
    __shared__ ushort Bs[2][128 * 64];
    const int tid = threadIdx.x;
    const int w = tid >> 6, lane = tid & 63;
    const int fr = lane & 15, fq = lane >> 4;
    const int m0 = blockIdx.x * 128, n0 = blockIdx.y * 128;
    const int wm = w & 1, wn = w >> 1;

    // staging: LDS dest linear (wave-uniform + lane*16B); global source pre-swizzled
    const int srow8 = lane >> 3;                       // 0..7
    const int scol  = ((lane & 7) ^ srow8) << 3;       // inverse-swizzled source chunk
    const ushort* gA[4]; const ushort* gB[4]; int fa[4];
#pragma unroll
    for (int j = 0; j < 4; ++j) {
        int rowj = (j * 4 + w) * 8 + srow8;
        fa[j] = (j * 4 + w) * 512 + lane * 8;
        gA[j] = A  + (size_t)(m0 + rowj) * lda + scol;
        gB[j] = Wt + (size_t)(n0 + rowj) * ldw + scol;
    }
    const int nt = K / 64;
#pragma unroll
    for (int j = 0; j < 4; ++j) {
        gl_lds16(gA[j], &As[0][fa[j]]); gl_lds16(gB[j], &Bs[0][fa[j]]);
        gA[j] += 64; gB[j] += 64;
    }
    f32x4 acc[4][4] = {};
    int cur = 0;
    for (int t = 0; t < nt; ++t) {
        __syncthreads();                 // drains vmcnt -> buf[cur] ready
        if (t + 1 < nt) {
#pragma unroll
            for (int j = 0; j < 4; ++j) {
                gl_lds16(gA[j], &As[cur ^ 1][fa[j]]); gl_lds16(gB[j], &Bs[cur ^ 1][fa[j]]);
                gA[j] += 64; gB[j] += 64;
            }
        }
#pragma unroll
        for (int s = 0; s < 2; ++s) {
            const int csw = ((s * 4 + fq) ^ (fr & 7)) << 3;   // swizzled chunk (mi/ni-independent)
            short8 af[4], bv[4];
#pragma unroll
            for (int mi = 0; mi < 4; ++mi)
                af[mi] = *(const short8*)(&As[cur][(wm * 64 + mi * 16 + fr) * 64 + csw]);
#pragma unroll
            for (int ni = 0; ni < 4; ++ni)
                bv[ni] = *(const short8*)(&Bs[cur][(wn * 64 + ni * 16 + fr) * 64 + csw]);
#pragma unroll
            for (int mi = 0; mi < 4; ++mi)
#pragma unroll
                for (int ni = 0; ni < 4; ++ni)
                    acc[mi][ni] = __builtin_amdgcn_mfma_f32_16x16x32_bf16(af[mi], bv[ni], acc[mi][ni], 0, 0, 0);
        }
        cur ^= 1;
    }
#pragma unroll
    for (int mi = 0; mi < 4; ++mi) {
#pragma unroll
        for (int ni = 0; ni < 4; ++ni) {
            int n = n0 + wn * 64 + ni * 16 + fr;
            float bvs = bias[n];
#pragma unroll
            for (int r = 0; r < 4; ++r) {
                int m = m0 + wm * 64 + mi * 16 + fq * 4 + r;
                C[(size_t)m * ldc + n] = f2bf(acc[mi][ni][r] + bvs);
            }
        }
    }
}

// ---------------- KAN layer 1: 32-row blocks, BK=64, split-K=4, swizzled LDS ----------------
__global__ __launch_bounds__(256) void kan1_mfma(const ushort* __restrict__ acat,   // [B][1600] bf16 (cols 0:1024)
                                                 const ushort* __restrict__ w1aug,  // [64][9216] pre-swizzled
                                                 const float* __restrict__ grid1,
                                                 float* __restrict__ midp) {
    __shared__ ushort As[32 * 64];
    __shared__ ushort Bs[64 * 64];
    const int tid = threadIdx.x;
    const int w = tid >> 6, lane = tid & 63;
    const int fr = lane & 15, fq = lane >> 4;
    const int m0 = blockIdx.x * 32;
    const int kb = blockIdx.y;
    const int kstart = kb * 2304;
    const float g0 = grid1[0];
    const float inv_h = 1.0f / (grid1[1] - g0);

    const int srow = tid >> 3, sc = tid & 7;
    ushort* aWr = As + srow * 64 + ((sc ^ (srow & 7)) << 3);
    const ushort* combRow = acat + (size_t)(m0 + srow) * 1600;

    const int bn = tid >> 3, bpc = tid & 7;
    const ushort* gB0 = w1aug + (size_t)bn * 9216 + kstart + bpc * 8;
    const ushort* gB1 = w1aug + (size_t)(bn + 32) * 9216 + kstart + bpc * 8;
    ushort* lB0 = Bs + tid * 8;
    ushort* lB1 = Bs + 2048 + tid * 8;

    const int wm = w & 1, wn = w >> 1;
    const int arow = wm * 16 + fr;
    const ushort* aRd = As + arow * 64;
    const int axor = arow & 7;

    f32x4 acc[2] = {};
    for (int step = 0; step < 36; ++step) {
        const int k0 = kstart + step * 64;
        gl_lds16(gB0, lB0); gl_lds16(gB1, lB1);
        gB0 += 64; gB1 += 64;
        uint o[4];
        if (k0 < 1024) {
            uint4 raw = *(const uint4*)(combRow + k0 + sc * 8);
            uint rr[4] = {raw.x, raw.y, raw.z, raw.w};
#pragma unroll
            for (int p = 0; p < 4; ++p) {
                float loF = siluf_(bf2f(rr[p] & 0xffffu));
                float hiF = siluf_(bf2f(rr[p] >> 16));
                o[p] = pack_trunc(loF, hiF);
            }
        } else {
            int i = ((k0 - 1024) >> 3) + sc;
            float x = bf2f((uint)combRow[i]);
            bases_packed(x, g0, inv_h, o);
        }
        uint4 o4; o4.x = o[0]; o4.y = o[1]; o4.z = o[2]; o4.w = o[3];
        *(uint4*)aWr = o4;
        __syncthreads();
#pragma unroll
        for (int s = 0; s < 2; ++s) {
            short8 af = *(const short8*)(aRd + (((s * 4 + fq) ^ axor) << 3));
#pragma unroll
            for (int ni = 0; ni < 2; ++ni) {
                int n = wn * 32 + ni * 16 + fr;
                short8 bv = *(const short8*)(Bs + n * 64 + (((s * 4 + fq) ^ (n & 7)) << 3));
                acc[ni] = __builtin_amdgcn_mfma_f32_16x16x32_bf16(af, bv, acc[ni], 0, 0, 0);
            }
        }
        __syncthreads();
    }
    float* outp = midp + (size_t)kb * (BATCH * 64);
#pragma unroll
    for (int ni = 0; ni < 2; ++ni)
#pragma unroll
        for (int r = 0; r < 4; ++r)
            outp[(size_t)(m0 + wm * 16 + fq * 4 + r) * 64 + wn * 32 + ni * 16 + fr] = acc[ni][r];
}

// ---------------- Acat[:,1024:1600] = [silu(mid) | bases(mid)], summing 4 partials ----------------
__global__ __launch_bounds__(256) void bs2_kernel(const float* __restrict__ midp,
                                                  const float* __restrict__ grid2,
                                                  ushort* __restrict__ acat) {
    int t = blockIdx.x * 256 + threadIdx.x;     // B*64
    if (t >= BATCH * 64) return;
    float x = midp[t] + midp[BATCH * 64 + t] + midp[2 * BATCH * 64 + t] + midp[3 * BATCH * 64 + t];
    int b = t >> 6, i = t & 63;
    float g0 = grid2[0], inv_h = 1.0f / (grid2[1] - g0);
    acat[(size_t)b * 1600 + 1024 + i] = f2bf(siluf_(x));
    uint o[4];
    bases_packed(x, g0, inv_h, o);
    uint4 o4; o4.x = o[0]; o4.y = o[1]; o4.z = o[2]; o4.w = o[3];
    *(uint4*)&acat[(size_t)b * 1600 + 1088 + i * 8] = o4;
}

// ---------------- fused gate + double-LN + blend ----------------
__device__ __forceinline__ void block_reduce_2(float& a, float& b, float (*red)[4]) {
#pragma unroll
    for (int off = 32; off; off >>= 1) {
        a += __shfl_xor(a, off, 64);
        b += __shfl_xor(b, off, 64);
    }
    int lane = threadIdx.x & 63, wid = threadIdx.x >> 6;
    if (lane == 0) { red[0][wid] = a; red[1][wid] = b; }
    __syncthreads();
    a = red[0][0] + red[0][1] + red[0][2] + red[0][3];
    b = red[1][0] + red[1][1] + red[1][2] + red[1][3];
}

__global__ __launch_bounds__(256) void final2(const ushort* __restrict__ ug,
                                              const ushort* __restrict__ hcb,
                                              const float* __restrict__ hprev,
                                              const float* __restrict__ ug_g,
                                              const float* __restrict__ ug_beta,
                                              const float* __restrict__ cg,
                                              const float* __restrict__ cb,
                                              float* __restrict__ out) {
    int row = blockIdx.x, tid = threadIdx.x;
    __shared__ float rA[2][4], rB[2][4], rC[2][4];
    float u0 = bf2f((uint)ug[(size_t)row * 512 + tid]);
    float u1 = bf2f((uint)ug[(size_t)row * 512 + tid + 256]);
    float h0 = bf2f((uint)hcb[(size_t)row * 512 + tid]);
    float h1 = bf2f((uint)hcb[(size_t)row * 512 + tid + 256]);
    float s = u0 + u1, ss = u0 * u0 + u1 * u1;
    block_reduce_2(s, ss, rA);
    float mu = s * (1.0f / 512.0f);
    float var = ss * (1.0f / 512.0f) - mu * mu;
    float r = rsqrtf(var + 1e-5f);
    float uu0 = sigmoidf_((u0 - mu) * r * ug_g[tid] + ug_beta[tid]);
    float uu1 = sigmoidf_((u1 - mu) * r * ug_g[tid + 256] + ug_beta[tid + 256]);
    float cg0 = cg[tid], cg1 = cg[tid + 256], cb0 = cb[tid], cb1 = cb[tid + 256];
    float s2 = h0 + h1, ss2 = h0 * h0 + h1 * h1;
    block_reduce_2(s2, ss2, rB);
    float mu2 = s2 * (1.0f / 512.0f);
    float var2 = ss2 * (1.0f / 512.0f) - mu2 * mu2;
    float r2 = rsqrtf(var2 + 1e-5f);
    float w0 = (h0 - mu2) * r2 * cg0 + cb0;
    float w1 = (h1 - mu2) * r2 * cg1 + cb1;
    float s3 = w0 + w1, ss3 = w0 * w0 + w1 * w1;
    block_reduce_2(s3, ss3, rC);
    float mu3 = s3 * (1.0f / 512.0f);
    float var3 = ss3 * (1.0f / 512.0f) - mu3 * mu3;
    float r3 = rsqrtf(var3 + 1e-5f);
    float c0 = siluf_((w0 - mu3) * r3 * cg0 + cb0);
    float c1 = siluf_((w1 - mu3) * r3 * cg1 + cb1);
    size_t o0 = (size_t)row * 512 + tid, o1 = o0 + 256;
    float hp0 = hprev[o0], hp1 = hprev[o1];
    out[o0] = (1.0f - uu0) * hp0 + uu0 * c0;
    out[o1] = (1.0f - uu1) * hp1 + uu1 * c1;
}

extern "C" void kernel_launch(void* const* d_in, const int* in_sizes, int n_in,
                              void* d_out, int out_size, void* d_ws, size_t ws_size,
                              hipStream_t stream) {
    const float* x        = (const float*)d_in[0];
    const float* h_prev   = (const float*)d_in[1];
    const float* ip_w     = (const float*)d_in[2];
    const float* ip_b     = (const float*)d_in[3];
    // d_in[4..7] rg_* : dead (reset gate unused in h_t)
    const float* ug_w     = (const float*)d_in[8];
    const float* ug_b     = (const float*)d_in[9];
    const float* ug_g     = (const float*)d_in[10];
    const float* ug_beta  = (const float*)d_in[11];
    const float* k1_base  = (const float*)d_in[12];
    const float* k1_spline= (const float*)d_in[13];
    const float* k1_scaler= (const float*)d_in[14];
    const float* grid1    = (const float*)d_in[15];
    const float* k2_base  = (const float*)d_in[16];
    const float* k2_spline= (const float*)d_in[17];
    const float* k2_scaler= (const float*)d_in[18];
    const float* grid2    = (const float*)d_in[19];
    const float* cn_g     = (const float*)d_in[20];
    const float* cn_b     = (const float*)d_in[21];
    const float* rp_w     = (const float*)d_in[22];
    const float* rp_b     = (const float*)d_in[23];
    float* out = (float*)d_out;
    char* W = (char*)d_ws;

    ushort* Acat   = (ushort*)(W);                    // 52,428,800 B  [B][1600]
    ushort* ug_bf  = (ushort*)(W + 52428800);         // 16,777,216 B  [B][512]
    ushort* hc_bf  = (ushort*)(W + 69206016);         // 16,777,216 B  [B][512]
    float*  midp   = (float*) (W + 85983232);         // 16,777,216 B  4x[B][64]
    ushort* x_bf   = (ushort*)(W + 102760448);        //  8,388,608 B
    ushort* ipw_bf = (ushort*)(W + 111149056);        //    262,144 B
    ushort* ugw_bf = (ushort*)(W + 111411200);        //  1,048,576 B
    ushort* wcat   = (ushort*)(W + 112459776);        //  1,638,400 B  [512][1600]
    ushort* w1aug  = (ushort*)(W + 114098176);        //  1,179,648 B  (pre-swizzled)

    // --- prep ---
    hipLaunchKernelGGL(cvt_bf, dim3(2048), dim3(256), 0, stream, x, x_bf, BATCH * 256 / 8);
    hipLaunchKernelGGL(cvt_bf, dim3(64),   dim3(256), 0, stream, ip_w, ipw_bf, 512 * 256 / 8);
    hipLaunchKernelGGL(cvt_bf, dim3(256),  dim3(256), 0, stream, ug_w, ugw_bf, 512 * 1024 / 8);
    hipLaunchKernelGGL(prep_wcat, dim3(3200), dim3(256), 0, stream, rp_w, k2_base, k2_spline, k2_scaler, wcat);
    hipLaunchKernelGGL(prep_w1aug, dim3(2304), dim3(256), 0, stream, k1_base, k1_spline, k1_scaler, w1aug);
    hipLaunchKernelGGL(copy_h_bf, dim3(4096), dim3(256), 0, stream, h_prev, Acat);

    // --- Acat[:, 0:512] = bf16(x @ ip_w.T + ip_b) ---
    hipLaunchKernelGGL(gemm_mfma, dim3(BATCH / 128, 4), dim3(256), 0, stream,
                       x_bf, 256, ipw_bf, 256, ip_b, Acat, 1600, 256);

    // --- ug_pre = bf16(comb @ ug_w.T + ug_b) ---
    hipLaunchKernelGGL(gemm_mfma, dim3(BATCH / 128, 4), dim3(256), 0, stream,
                       Acat, 1600, ugw_bf, 1024, ug_b, ug_bf, 512, 1024);

    // --- KAN1 (split-K=4) -> midp -> Acat[:,1024:1600] ---
    hipLaunchKernelGGL(kan1_mfma, dim3(BATCH / 32, 4), dim3(256), 0, stream, Acat, w1aug, grid1, midp);
    hipLaunchKernelGGL(bs2_kernel, dim3(BATCH * 64 / 256), dim3(256), 0, stream, midp, grid2, Acat);

    // --- hc = bf16(Acat @ Wcat.T + rp_b)  (residual + KAN2 in one GEMM) ---
    hipLaunchKernelGGL(gemm_mfma, dim3(BATCH / 128, 4), dim3(256), 0, stream,
                       Acat, 1600, wcat, 1600, rp_b, hc_bf, 512, 1600);

    // --- h_t ---
    hipLaunchKernelGGL(final2, dim3(BATCH), dim3(256), 0, stream, ug_bf, hc_bf, h_prev, ug_g, ug_beta, cn_g, cn_b, out);
}